// Round 4
// baseline (490.335 us; speedup 1.0000x reference)
//
#include <hip/hip_runtime.h>

#define N_NODES 80000
#define N_EDGES 1280000
#define D 64            // D_IN == D_OUT == 64
#define NB 1250         // bins of 64 nodes: 1250*64 = 80000
#define NPB 64          // nodes per bin
#define CAPB 1536       // per-bin record capacity (Poisson(1024) + ~16 sigma)
#define PT 1024         // partition block threads
#define EPT 5           // edges per partition thread
#define EPB (PT * EPT)  // 5120 edges per partition block
#define NBLK (N_EDGES / EPB)  // 250 partition blocks (exact)

// ---------------- workspace layout (bytes) ----------------
#define OFF_SUP   0u
#define SUP_BYTES (N_NODES * D * 2u)                 // 10,240,000 (bf16 support)
#define OFF_CNT   (OFF_SUP + SUP_BYTES)
#define CNT_BYTES (NB * 4u)                          // 5,000
#define OFF_OVC   (OFF_CNT + 5120u)
#define OFF_REC   (OFF_OVC + 256u)                   // 16B-aligned
#define REC_BYTES (NB * CAPB * 8u)                   // 15,360,000
#define OFF_OVF   (OFF_REC + REC_BYTES)
#define OVF_BYTES (N_EDGES * 4u)

// round-to-nearest-even f32 -> bf16 pair packed in one uint (a=lo, b=hi)
__device__ inline unsigned bf16pair(float a, float b) {
    unsigned ua = __float_as_uint(a);
    unsigned ub = __float_as_uint(b);
    ua = (ua + 0x7fffu + ((ua >> 16) & 1u)) >> 16;
    ub = (ub + 0x7fffu + ((ub >> 16) & 1u)) & 0xffff0000u;
    return ua | ub;
}

// ---------------------------------------------------------------------------
// Kernel 1: support = X @ W  -> bf16   (one thread per row; W staged in LDS)
// ---------------------------------------------------------------------------
__global__ __launch_bounds__(256) void gemm_xw(const float* __restrict__ x,
                                               const float* __restrict__ w,
                                               unsigned* __restrict__ sup) {
    __shared__ float4 Ws[D * 16];
    const int tid = threadIdx.x;
    for (int i = tid; i < D * 16; i += 256) Ws[i] = ((const float4*)w)[i];
    __syncthreads();

    const int row = blockIdx.x * 256 + tid;
    if (row >= N_NODES) return;

    const float4* xr = (const float4*)(x + (size_t)row * D);
    float4 acc[16];
#pragma unroll
    for (int j = 0; j < 16; ++j) acc[j] = make_float4(0.f, 0.f, 0.f, 0.f);

    for (int k4 = 0; k4 < 16; ++k4) {
        const float4 xv = xr[k4];
        const float xs[4] = {xv.x, xv.y, xv.z, xv.w};
#pragma unroll
        for (int kk = 0; kk < 4; ++kk) {
            const float xk = xs[kk];
            const int k = k4 * 4 + kk;
#pragma unroll
            for (int j = 0; j < 16; ++j) {
                const float4 wv = Ws[k * 16 + j];
                acc[j].x += xk * wv.x;
                acc[j].y += xk * wv.y;
                acc[j].z += xk * wv.z;
                acc[j].w += xk * wv.w;
            }
        }
    }

    unsigned* srow = sup + (size_t)row * 32;
#pragma unroll
    for (int j = 0; j < 8; ++j) {
        uint4 u;
        u.x = bf16pair(acc[2 * j].x,     acc[2 * j].y);
        u.y = bf16pair(acc[2 * j].z,     acc[2 * j].w);
        u.z = bf16pair(acc[2 * j + 1].x, acc[2 * j + 1].y);
        u.w = bf16pair(acc[2 * j + 1].z, acc[2 * j + 1].w);
        ((uint4*)srow)[j] = u;
    }
}

// ---------------------------------------------------------------------------
// Kernel 2: block-batched partition.  Per block: LDS histogram of 5120 edges
// over 1250 bins -> ONE global atomic per non-empty bin (range reservation)
// -> LDS-cursor placement into per-bin contiguous streams.
// record = (src | dst_lo<<17, weight)
// ---------------------------------------------------------------------------
__global__ __launch_bounds__(PT) void partition_block(const int* __restrict__ ei,
                                                      const float* __restrict__ ew,
                                                      int* __restrict__ cnt,
                                                      int2* __restrict__ recs,
                                                      int* __restrict__ ovf_cnt,
                                                      int* __restrict__ ovf_list) {
    __shared__ int hist[NB];   // count, then reused as global-slot cursor
    const int tid = threadIdx.x;
    const int e0 = blockIdx.x * EPB;

    for (int i = tid; i < NB; i += PT) hist[i] = 0;
    __syncthreads();

    int r_meta[EPT], r_w[EPT], r_bin[EPT];
#pragma unroll
    for (int i = 0; i < EPT; ++i) {
        const int e = e0 + i * PT + tid;
        const int dst = ei[N_EDGES + e];
        const int src = ei[e];
        r_meta[i] = src | ((dst & 63) << 17);
        r_w[i]    = __float_as_int(ew[e]);
        r_bin[i]  = dst >> 6;
        atomicAdd(&hist[r_bin[i]], 1);
    }
    __syncthreads();

    // reserve a contiguous global range per non-empty bin; hist <- global base
    for (int b = tid; b < NB; b += PT) {
        const int c = hist[b];
        if (c > 0) hist[b] = atomicAdd(&cnt[b], c);
    }
    __syncthreads();

    // place records at base + local rank (LDS cursor gives global slot)
#pragma unroll
    for (int i = 0; i < EPT; ++i) {
        const int slot = atomicAdd(&hist[r_bin[i]], 1);
        if (slot < CAPB) {
            recs[(size_t)r_bin[i] * CAPB + slot] = make_int2(r_meta[i], r_w[i]);
        } else {
            const int q = atomicAdd(ovf_cnt, 1);
            ovf_list[q] = e0 + i * PT + tid;
        }
    }
}

// ---------------------------------------------------------------------------
// Kernel 3: per-bin gather into LDS f32 accumulators (bias-initialized),
// then one coalesced out write.  16-lane group per record.
// ---------------------------------------------------------------------------
__global__ __launch_bounds__(256) void gather_bins(const unsigned* __restrict__ sup,
                                                   const int* __restrict__ cnt,
                                                   const int2* __restrict__ recs,
                                                   const float* __restrict__ bias,
                                                   float* __restrict__ out) {
    __shared__ float acc[NPB * D];   // 16 KB
    const int tid = threadIdx.x;
    const int bin = blockIdx.x;

    for (int i = tid; i < NPB * D; i += 256) acc[i] = bias[i & 63];
    __syncthreads();

    int c = cnt[bin];
    c = c < CAPB ? c : CAPB;
    const int2* bk = recs + (size_t)bin * CAPB;
    const int g = tid >> 4;
    const int l = tid & 15;

    for (int k = g; k < c; k += 16) {
        const int2 r = bk[k];                         // 16 lanes same addr: broadcast
        const float w = __int_as_float(r.y);
        const int src = r.x & 0x1FFFF;
        const int n = (r.x >> 17) & 63;
        const uint2 sv = ((const uint2*)(sup + (size_t)src * 32))[l];
        float* a = acc + n * D + l * 4;
        atomicAdd(a + 0, w * __uint_as_float(sv.x << 16));
        atomicAdd(a + 1, w * __uint_as_float(sv.x & 0xffff0000u));
        atomicAdd(a + 2, w * __uint_as_float(sv.y << 16));
        atomicAdd(a + 3, w * __uint_as_float(sv.y & 0xffff0000u));
    }
    __syncthreads();

    const float4* af = (const float4*)acc;
    float4* og = (float4*)(out + (size_t)bin * NPB * D);
    for (int i = tid; i < NPB * 16; i += 256) og[i] = af[i];
}

// ---------------------------------------------------------------------------
// Kernel 4: rare overflow edges -> atomic scatter (statistically zero work)
// ---------------------------------------------------------------------------
__global__ __launch_bounds__(256) void scatter_ovf(const int* __restrict__ ei,
                                                   const float* __restrict__ ew,
                                                   const unsigned* __restrict__ sup,
                                                   const int* __restrict__ ovf_cnt,
                                                   const int* __restrict__ ovf_list,
                                                   float* __restrict__ out) {
    const int n = *ovf_cnt;
    for (int i = blockIdx.x * 256 + threadIdx.x; i < n; i += gridDim.x * 256) {
        const int e = ovf_list[i];
        const int src = ei[e];
        const int dst = ei[N_EDGES + e];
        const float w = ew[e];
        const unsigned* s = sup + (size_t)src * 32;
        float* o = out + (size_t)dst * D;
        for (int j = 0; j < 32; ++j) {
            const unsigned u = s[j];
            atomicAdd(o + 2 * j,     w * __uint_as_float(u << 16));
            atomicAdd(o + 2 * j + 1, w * __uint_as_float(u & 0xffff0000u));
        }
    }
}

// ---------------------------------------------------------------------------
extern "C" void kernel_launch(void* const* d_in, const int* in_sizes, int n_in,
                              void* d_out, int out_size, void* d_ws, size_t ws_size,
                              hipStream_t stream) {
    const float* x      = (const float*)d_in[0];
    const int*   ei     = (const int*)d_in[1];
    const float* ew     = (const float*)d_in[2];
    const float* weight = (const float*)d_in[3];
    const float* bias   = (const float*)d_in[4];
    float* out = (float*)d_out;

    char* ws = (char*)d_ws;
    unsigned* sup   = (unsigned*)(ws + OFF_SUP);
    int*  cnt       = (int*)(ws + OFF_CNT);
    int*  ovf_cnt   = (int*)(ws + OFF_OVC);
    int2* recs      = (int2*)(ws + OFF_REC);
    int*  ovf_list  = (int*)(ws + OFF_OVF);

    // 1. support = X @ W (bf16)
    gemm_xw<<<(N_NODES + 255) / 256, 256, 0, stream>>>(x, weight, sup);

    // 2. zero bin counters + overflow counter
    hipMemsetAsync(ws + OFF_CNT, 0, (OFF_REC - OFF_CNT), stream);

    // 3. block-batched partition into per-bin streams
    partition_block<<<NBLK, PT, 0, stream>>>(ei, ew, cnt, recs, ovf_cnt, ovf_list);

    // 4. per-bin gather + bias + out write
    gather_bins<<<NB, 256, 0, stream>>>(sup, cnt, recs, bias, out);

    // 5. overflow cleanup (statistically empty, correctness safety net)
    scatter_ovf<<<64, 256, 0, stream>>>(ei, ew, sup, ovf_cnt, ovf_list, out);
}

// Round 5
// 104.850 us; speedup vs baseline: 4.6766x; 4.6766x over previous
//
#include <hip/hip_runtime.h>

#define N_NODES 80000
#define N_EDGES 1280000
#define D 64            // D_IN == D_OUT == 64
#define NB 1250         // bins of 64 nodes: 1250*64 = 80000
#define NPB 64          // nodes per bin
#define CAPB 1536       // per-bin record capacity (Poisson(1024) + ~16 sigma)
#define PT 1024         // partition block threads
#define EPT 5           // edges per partition thread
#define EPB (PT * EPT)  // 5120 edges per partition block
#define NBLK (N_EDGES / EPB)  // 250 partition blocks (exact)

// ---------------- workspace layout (bytes) ----------------
#define OFF_SUP   0u
#define SUP_BYTES (N_NODES * D * 2u)                 // 10,240,000 (bf16 support)
#define OFF_CNT   (OFF_SUP + SUP_BYTES)
#define OFF_OVC   (OFF_CNT + 5120u)
#define OFF_REC   (OFF_OVC + 256u)
#define REC_BYTES (NB * CAPB * 8u)                   // 15,360,000
#define OFF_OVF   (OFF_REC + REC_BYTES)

// round-to-nearest-even f32 -> bf16 pair packed in one uint (a=lo, b=hi)
__device__ inline unsigned bf16pair(float a, float b) {
    unsigned ua = __float_as_uint(a);
    unsigned ub = __float_as_uint(b);
    ua = (ua + 0x7fffu + ((ua >> 16) & 1u)) >> 16;
    ub = (ub + 0x7fffu + ((ub >> 16) & 1u)) & 0xffff0000u;
    return ua | ub;
}

// ---------------------------------------------------------------------------
// Kernel 1: support = X @ W  -> bf16   (one thread per row; W staged in LDS)
// ---------------------------------------------------------------------------
__global__ __launch_bounds__(256) void gemm_xw(const float* __restrict__ x,
                                               const float* __restrict__ w,
                                               unsigned* __restrict__ sup) {
    __shared__ float4 Ws[D * 16];
    const int tid = threadIdx.x;
    for (int i = tid; i < D * 16; i += 256) Ws[i] = ((const float4*)w)[i];
    __syncthreads();

    const int row = blockIdx.x * 256 + tid;
    if (row >= N_NODES) return;

    const float4* xr = (const float4*)(x + (size_t)row * D);
    float4 acc[16];
#pragma unroll
    for (int j = 0; j < 16; ++j) acc[j] = make_float4(0.f, 0.f, 0.f, 0.f);

    for (int k4 = 0; k4 < 16; ++k4) {
        const float4 xv = xr[k4];
        const float xs[4] = {xv.x, xv.y, xv.z, xv.w};
#pragma unroll
        for (int kk = 0; kk < 4; ++kk) {
            const float xk = xs[kk];
            const int k = k4 * 4 + kk;
#pragma unroll
            for (int j = 0; j < 16; ++j) {
                const float4 wv = Ws[k * 16 + j];
                acc[j].x += xk * wv.x;
                acc[j].y += xk * wv.y;
                acc[j].z += xk * wv.z;
                acc[j].w += xk * wv.w;
            }
        }
    }

    unsigned* srow = sup + (size_t)row * 32;
#pragma unroll
    for (int j = 0; j < 8; ++j) {
        uint4 u;
        u.x = bf16pair(acc[2 * j].x,     acc[2 * j].y);
        u.y = bf16pair(acc[2 * j].z,     acc[2 * j].w);
        u.z = bf16pair(acc[2 * j + 1].x, acc[2 * j + 1].y);
        u.w = bf16pair(acc[2 * j + 1].z, acc[2 * j + 1].w);
        ((uint4*)srow)[j] = u;
    }
}

// ---------------------------------------------------------------------------
// Kernel 2: block-batched partition (round-4 version, measured fast).
// Per block: LDS histogram of 5120 edges over 1250 bins -> one global atomic
// per non-empty bin -> LDS-cursor placement into per-bin contiguous streams.
// record = (src | dst_lo<<17, weight)
// ---------------------------------------------------------------------------
__global__ __launch_bounds__(PT) void partition_block(const int* __restrict__ ei,
                                                      const float* __restrict__ ew,
                                                      int* __restrict__ cnt,
                                                      int2* __restrict__ recs,
                                                      int* __restrict__ ovf_cnt,
                                                      int* __restrict__ ovf_list) {
    __shared__ int hist[NB];   // count, then reused as global-slot cursor
    const int tid = threadIdx.x;
    const int e0 = blockIdx.x * EPB;

    for (int i = tid; i < NB; i += PT) hist[i] = 0;
    __syncthreads();

    int r_meta[EPT], r_w[EPT], r_bin[EPT];
#pragma unroll
    for (int i = 0; i < EPT; ++i) {
        const int e = e0 + i * PT + tid;
        const int dst = ei[N_EDGES + e];
        const int src = ei[e];
        r_meta[i] = src | ((dst & 63) << 17);
        r_w[i]    = __float_as_int(ew[e]);
        r_bin[i]  = dst >> 6;
        atomicAdd(&hist[r_bin[i]], 1);
    }
    __syncthreads();

    for (int b = tid; b < NB; b += PT) {
        const int c = hist[b];
        if (c > 0) hist[b] = atomicAdd(&cnt[b], c);
    }
    __syncthreads();

#pragma unroll
    for (int i = 0; i < EPT; ++i) {
        const int slot = atomicAdd(&hist[r_bin[i]], 1);
        if (slot < CAPB) {
            recs[(size_t)r_bin[i] * CAPB + slot] = make_int2(r_meta[i], r_w[i]);
        } else {
            const int q = atomicAdd(ovf_cnt, 1);
            ovf_list[q] = e0 + i * PT + tid;
        }
    }
}

// ---------------------------------------------------------------------------
// Kernel 3: per-bin gather.  Stage records in LDS, build u16 permutation into
// per-node CSR order (int LDS atomics only), then 16-lane groups accumulate
// 4 nodes each in registers and write out once.
// ---------------------------------------------------------------------------
__global__ __launch_bounds__(256) void gather_bins(const unsigned* __restrict__ sup,
                                                   const int* __restrict__ cnt,
                                                   const int2* __restrict__ recs,
                                                   const float* __restrict__ bias,
                                                   float* __restrict__ out) {
    __shared__ int2 lrec[CAPB];              // 12,288 B
    __shared__ unsigned short perm[CAPB];    //  3,072 B
    __shared__ int lcnt[NPB];
    __shared__ int lcur[NPB];
    __shared__ int loff[NPB + 1];
    __shared__ float4 b4[16];

    const int tid = threadIdx.x;
    const int bin = blockIdx.x;

    if (tid < 16) b4[tid] = ((const float4*)bias)[tid];
    if (tid < NPB) lcnt[tid] = 0;
    __syncthreads();

    int c = cnt[bin];
    c = c < CAPB ? c : CAPB;
    const int2* bk = recs + (size_t)bin * CAPB;

    // stage + per-node counts (1 int LDS atomic per record)
    for (int i = tid; i < c; i += 256) {
        const int2 r = bk[i];
        lrec[i] = r;
        atomicAdd(&lcnt[(r.x >> 17) & 63], 1);
    }
    __syncthreads();

    // wave 0: exclusive scan over 64 node counts
    if (tid < 64) {
        const int my = lcnt[tid];
        int v = my;
#pragma unroll
        for (int d = 1; d < 64; d <<= 1) {
            const int o = __shfl_up(v, d);
            if (tid >= d) v += o;
        }
        loff[tid + 1] = v;
        lcur[tid] = v - my;
        if (tid == 0) loff[0] = 0;
    }
    __syncthreads();

    // permutation into CSR order (1 int LDS atomic + u16 write per record)
    for (int i = tid; i < c; i += 256) {
        const int pos = atomicAdd(&lcur[(lrec[i].x >> 17) & 63], 1);
        perm[pos] = (unsigned short)i;
    }
    __syncthreads();

    // gather: 16 groups x 16 lanes; 4 nodes per group, register accumulate
    const int g = tid >> 4;
    const int l = tid & 15;
#pragma unroll
    for (int jj = 0; jj < 4; ++jj) {
        const int n = g * 4 + jj;
        float4 acc = b4[l];
        const int kend = loff[n + 1];
        for (int k = loff[n]; k < kend; ++k) {
            const int2 r = lrec[perm[k]];             // broadcast in group
            const float w = __int_as_float(r.y);
            const uint2 sv = ((const uint2*)(sup + (size_t)(r.x & 0x1FFFF) * 32))[l];
            acc.x += w * __uint_as_float(sv.x << 16);
            acc.y += w * __uint_as_float(sv.x & 0xffff0000u);
            acc.z += w * __uint_as_float(sv.y << 16);
            acc.w += w * __uint_as_float(sv.y & 0xffff0000u);
        }
        ((float4*)out)[(size_t)(bin * NPB + n) * 16 + l] = acc;
    }
}

// ---------------------------------------------------------------------------
// Kernel 4: rare overflow edges -> atomic scatter (statistically zero work)
// ---------------------------------------------------------------------------
__global__ __launch_bounds__(256) void scatter_ovf(const int* __restrict__ ei,
                                                   const float* __restrict__ ew,
                                                   const unsigned* __restrict__ sup,
                                                   const int* __restrict__ ovf_cnt,
                                                   const int* __restrict__ ovf_list,
                                                   float* __restrict__ out) {
    const int n = *ovf_cnt;
    for (int i = blockIdx.x * 256 + threadIdx.x; i < n; i += gridDim.x * 256) {
        const int e = ovf_list[i];
        const int src = ei[e];
        const int dst = ei[N_EDGES + e];
        const float w = ew[e];
        const unsigned* s = sup + (size_t)src * 32;
        float* o = out + (size_t)dst * D;
        for (int j = 0; j < 32; ++j) {
            const unsigned u = s[j];
            atomicAdd(o + 2 * j,     w * __uint_as_float(u << 16));
            atomicAdd(o + 2 * j + 1, w * __uint_as_float(u & 0xffff0000u));
        }
    }
}

// ---------------------------------------------------------------------------
extern "C" void kernel_launch(void* const* d_in, const int* in_sizes, int n_in,
                              void* d_out, int out_size, void* d_ws, size_t ws_size,
                              hipStream_t stream) {
    const float* x      = (const float*)d_in[0];
    const int*   ei     = (const int*)d_in[1];
    const float* ew     = (const float*)d_in[2];
    const float* weight = (const float*)d_in[3];
    const float* bias   = (const float*)d_in[4];
    float* out = (float*)d_out;

    char* ws = (char*)d_ws;
    unsigned* sup   = (unsigned*)(ws + OFF_SUP);
    int*  cnt       = (int*)(ws + OFF_CNT);
    int*  ovf_cnt   = (int*)(ws + OFF_OVC);
    int2* recs      = (int2*)(ws + OFF_REC);
    int*  ovf_list  = (int*)(ws + OFF_OVF);

    // 1. support = X @ W (bf16)
    gemm_xw<<<(N_NODES + 255) / 256, 256, 0, stream>>>(x, weight, sup);

    // 2. zero bin counters + overflow counter
    hipMemsetAsync(ws + OFF_CNT, 0, (OFF_REC - OFF_CNT), stream);

    // 3. block-batched partition into per-bin contiguous streams
    partition_block<<<NBLK, PT, 0, stream>>>(ei, ew, cnt, recs, ovf_cnt, ovf_list);

    // 4. per-bin gather + bias + out write (register accumulation)
    gather_bins<<<NB, 256, 0, stream>>>(sup, cnt, recs, bias, out);

    // 5. overflow cleanup (statistically empty, correctness safety net)
    scatter_ovf<<<64, 256, 0, stream>>>(ei, ew, sup, ovf_cnt, ovf_list, out);
}

// Round 6
// 97.716 us; speedup vs baseline: 5.0179x; 1.0730x over previous
//
#include <hip/hip_runtime.h>

#define N_NODES 80000
#define N_EDGES 1280000
#define D 64            // D_IN == D_OUT == 64
#define NB 1250         // bins of 64 nodes: 1250*64 = 80000
#define NPB 64          // nodes per bin
#define CAPB 1536       // per-bin record capacity (Poisson(1024) + ~16 sigma)
#define PT 1024         // partition block threads
#define EPT 5           // edges per partition thread
#define EPB (PT * EPT)  // 5120 edges per partition block
#define NBLK (N_EDGES / EPB)  // 250 partition blocks (exact)

// ---------------- workspace layout (bytes) ----------------
#define OFF_SUP   0u
#define SUP_BYTES (N_NODES * D * 2u)                 // 10,240,000 (bf16 support)
#define OFF_CNT   (OFF_SUP + SUP_BYTES)
#define OFF_OVC   (OFF_CNT + 5120u)
#define OFF_REC   (OFF_OVC + 256u)
#define REC_BYTES (NB * CAPB * 8u)                   // 15,360,000
#define OFF_OVF   (OFF_REC + REC_BYTES)

// round-to-nearest-even f32 -> bf16 pair packed in one uint (a=lo, b=hi)
__device__ inline unsigned bf16pair(float a, float b) {
    unsigned ua = __float_as_uint(a);
    unsigned ub = __float_as_uint(b);
    ua = (ua + 0x7fffu + ((ua >> 16) & 1u)) >> 16;
    ub = (ub + 0x7fffu + ((ub >> 16) & 1u)) & 0xffff0000u;
    return ua | ub;
}

// ---------------------------------------------------------------------------
// Kernel 1: support = X @ W -> bf16.  512 threads: each row handled by 2
// threads (j-halves) -> 2x wave count vs round-5, half the serial chain.
// ---------------------------------------------------------------------------
__global__ __launch_bounds__(512) void gemm_xw(const float* __restrict__ x,
                                               const float* __restrict__ w,
                                               unsigned* __restrict__ sup) {
    __shared__ float4 Ws[D * 16];
    const int tid = threadIdx.x;
    for (int i = tid; i < D * 16; i += 512) Ws[i] = ((const float4*)w)[i];
    __syncthreads();

    const int h = tid >> 8;                 // j-half: 0 or 1
    const int row = blockIdx.x * 256 + (tid & 255);
    if (row >= N_NODES) return;

    const float4* xr = (const float4*)(x + (size_t)row * D);
    float4 acc[8];
#pragma unroll
    for (int j = 0; j < 8; ++j) acc[j] = make_float4(0.f, 0.f, 0.f, 0.f);

    for (int k4 = 0; k4 < 16; ++k4) {
        const float4 xv = xr[k4];
        const float xs[4] = {xv.x, xv.y, xv.z, xv.w};
#pragma unroll
        for (int kk = 0; kk < 4; ++kk) {
            const float xk = xs[kk];
            const int k = k4 * 4 + kk;
#pragma unroll
            for (int j = 0; j < 8; ++j) {
                const float4 wv = Ws[k * 16 + h * 8 + j];
                acc[j].x += xk * wv.x;
                acc[j].y += xk * wv.y;
                acc[j].z += xk * wv.z;
                acc[j].w += xk * wv.w;
            }
        }
    }

    // this half writes 16 uints (cols h*32 .. h*32+31) as 4 uint4 stores
    unsigned* srow = sup + (size_t)row * 32 + h * 16;
#pragma unroll
    for (int jj = 0; jj < 4; ++jj) {
        uint4 u;
        u.x = bf16pair(acc[2 * jj].x,     acc[2 * jj].y);
        u.y = bf16pair(acc[2 * jj].z,     acc[2 * jj].w);
        u.z = bf16pair(acc[2 * jj + 1].x, acc[2 * jj + 1].y);
        u.w = bf16pair(acc[2 * jj + 1].z, acc[2 * jj + 1].w);
        ((uint4*)srow)[jj] = u;
    }
}

// ---------------------------------------------------------------------------
// Kernel 2: block-batched partition (measured fast in round 5).
// record = (src | dst_lo<<17, weight)
// ---------------------------------------------------------------------------
__global__ __launch_bounds__(PT) void partition_block(const int* __restrict__ ei,
                                                      const float* __restrict__ ew,
                                                      int* __restrict__ cnt,
                                                      int2* __restrict__ recs,
                                                      int* __restrict__ ovf_cnt,
                                                      int* __restrict__ ovf_list) {
    __shared__ int hist[NB];   // count, then reused as global-slot cursor
    const int tid = threadIdx.x;
    const int e0 = blockIdx.x * EPB;

    for (int i = tid; i < NB; i += PT) hist[i] = 0;
    __syncthreads();

    int r_meta[EPT], r_w[EPT], r_bin[EPT];
#pragma unroll
    for (int i = 0; i < EPT; ++i) {
        const int e = e0 + i * PT + tid;
        const int dst = ei[N_EDGES + e];
        const int src = ei[e];
        r_meta[i] = src | ((dst & 63) << 17);
        r_w[i]    = __float_as_int(ew[e]);
        r_bin[i]  = dst >> 6;
        atomicAdd(&hist[r_bin[i]], 1);
    }
    __syncthreads();

    for (int b = tid; b < NB; b += PT) {
        const int c = hist[b];
        if (c > 0) hist[b] = atomicAdd(&cnt[b], c);
    }
    __syncthreads();

#pragma unroll
    for (int i = 0; i < EPT; ++i) {
        const int slot = atomicAdd(&hist[r_bin[i]], 1);
        if (slot < CAPB) {
            recs[(size_t)r_bin[i] * CAPB + slot] = make_int2(r_meta[i], r_w[i]);
        } else {
            const int q = atomicAdd(ovf_cnt, 1);
            ovf_list[q] = e0 + i * PT + tid;
        }
    }
}

// ---------------------------------------------------------------------------
// Kernel 3: per-bin gather, 1024 threads (16 waves): stage records, u16
// permutation to CSR order, then ONE 16-lane group per node with a
// software-pipelined record loop (next LDS+global load issued before FMA).
// ---------------------------------------------------------------------------
__global__ __launch_bounds__(1024) void gather_bins(const unsigned* __restrict__ sup,
                                                    const int* __restrict__ cnt,
                                                    const int2* __restrict__ recs,
                                                    const float* __restrict__ bias,
                                                    float* __restrict__ out) {
    __shared__ int2 lrec[CAPB];              // 12,288 B
    __shared__ unsigned short perm[CAPB];    //  3,072 B
    __shared__ int lcnt[NPB];
    __shared__ int lcur[NPB];
    __shared__ int loff[NPB + 1];
    __shared__ float4 b4[16];

    const int tid = threadIdx.x;
    const int bin = blockIdx.x;

    if (tid < 16) b4[tid] = ((const float4*)bias)[tid];
    if (tid < NPB) lcnt[tid] = 0;
    __syncthreads();

    int c = cnt[bin];
    c = c < CAPB ? c : CAPB;
    const int2* bk = recs + (size_t)bin * CAPB;

    // stage + per-node counts (1 int LDS atomic per record)
    for (int i = tid; i < c; i += 1024) {
        const int2 r = bk[i];
        lrec[i] = r;
        atomicAdd(&lcnt[(r.x >> 17) & 63], 1);
    }
    __syncthreads();

    // wave 0: exclusive scan over 64 node counts
    if (tid < 64) {
        const int my = lcnt[tid];
        int v = my;
#pragma unroll
        for (int d = 1; d < 64; d <<= 1) {
            const int o = __shfl_up(v, d);
            if (tid >= d) v += o;
        }
        loff[tid + 1] = v;
        lcur[tid] = v - my;
        if (tid == 0) loff[0] = 0;
    }
    __syncthreads();

    // permutation into CSR order (1 int LDS atomic + u16 write per record)
    for (int i = tid; i < c; i += 1024) {
        const int pos = atomicAdd(&lcur[(lrec[i].x >> 17) & 63], 1);
        perm[pos] = (unsigned short)i;
    }
    __syncthreads();

    // one 16-lane group per node; pipelined accumulate
    const int n = tid >> 4;       // node 0..63
    const int l = tid & 15;
    const int kbeg = loff[n];
    const int kend = loff[n + 1];
    float4 acc = b4[l];
    if (kbeg < kend) {
        int2 r = lrec[perm[kbeg]];
        uint2 sv = ((const uint2*)(sup + (size_t)(r.x & 0x1FFFF) * 32))[l];
        float wc = __int_as_float(r.y);
        for (int k = kbeg; k < kend; ++k) {
            const int kn = (k + 1 < kend) ? k + 1 : k;
            const int2 rn = lrec[perm[kn]];
            const uint2 svn = ((const uint2*)(sup + (size_t)(rn.x & 0x1FFFF) * 32))[l];
            acc.x += wc * __uint_as_float(sv.x << 16);
            acc.y += wc * __uint_as_float(sv.x & 0xffff0000u);
            acc.z += wc * __uint_as_float(sv.y << 16);
            acc.w += wc * __uint_as_float(sv.y & 0xffff0000u);
            sv = svn;
            wc = __int_as_float(rn.y);
        }
    }
    ((float4*)out)[(size_t)(bin * NPB + n) * 16 + l] = acc;
}

// ---------------------------------------------------------------------------
// Kernel 4: rare overflow edges -> atomic scatter (statistically zero work)
// ---------------------------------------------------------------------------
__global__ __launch_bounds__(256) void scatter_ovf(const int* __restrict__ ei,
                                                   const float* __restrict__ ew,
                                                   const unsigned* __restrict__ sup,
                                                   const int* __restrict__ ovf_cnt,
                                                   const int* __restrict__ ovf_list,
                                                   float* __restrict__ out) {
    const int n = *ovf_cnt;
    for (int i = blockIdx.x * 256 + threadIdx.x; i < n; i += gridDim.x * 256) {
        const int e = ovf_list[i];
        const int src = ei[e];
        const int dst = ei[N_EDGES + e];
        const float w = ew[e];
        const unsigned* s = sup + (size_t)src * 32;
        float* o = out + (size_t)dst * D;
        for (int j = 0; j < 32; ++j) {
            const unsigned u = s[j];
            atomicAdd(o + 2 * j,     w * __uint_as_float(u << 16));
            atomicAdd(o + 2 * j + 1, w * __uint_as_float(u & 0xffff0000u));
        }
    }
}

// ---------------------------------------------------------------------------
extern "C" void kernel_launch(void* const* d_in, const int* in_sizes, int n_in,
                              void* d_out, int out_size, void* d_ws, size_t ws_size,
                              hipStream_t stream) {
    const float* x      = (const float*)d_in[0];
    const int*   ei     = (const int*)d_in[1];
    const float* ew     = (const float*)d_in[2];
    const float* weight = (const float*)d_in[3];
    const float* bias   = (const float*)d_in[4];
    float* out = (float*)d_out;

    char* ws = (char*)d_ws;
    unsigned* sup   = (unsigned*)(ws + OFF_SUP);
    int*  cnt       = (int*)(ws + OFF_CNT);
    int*  ovf_cnt   = (int*)(ws + OFF_OVC);
    int2* recs      = (int2*)(ws + OFF_REC);
    int*  ovf_list  = (int*)(ws + OFF_OVF);

    // 1. support = X @ W (bf16), 512-thread row-split blocks
    gemm_xw<<<(N_NODES + 255) / 256, 512, 0, stream>>>(x, weight, sup);

    // 2. zero bin counters + overflow counter
    hipMemsetAsync(ws + OFF_CNT, 0, (OFF_REC - OFF_CNT), stream);

    // 3. block-batched partition into per-bin contiguous streams
    partition_block<<<NBLK, PT, 0, stream>>>(ei, ew, cnt, recs, ovf_cnt, ovf_list);

    // 4. per-bin gather + bias + out write (1024 threads, 1 group/node)
    gather_bins<<<NB, 1024, 0, stream>>>(sup, cnt, recs, bias, out);

    // 5. overflow cleanup (statistically empty, correctness safety net)
    scatter_ovf<<<64, 256, 0, stream>>>(ei, ew, sup, ovf_cnt, ovf_list, out);
}

// Round 7
// 95.653 us; speedup vs baseline: 5.1262x; 1.0216x over previous
//
#include <hip/hip_runtime.h>

#define N_NODES 80000
#define N_EDGES 1280000
#define D 64            // D_IN == D_OUT == 64
#define NB 1250         // bins of 64 nodes: 1250*64 = 80000
#define NPB 64          // nodes per bin
#define CAPB 1536       // per-bin record capacity (Poisson(1024) + ~16 sigma)
#define PT 1024         // partition block threads
#define EPT 5           // edges per partition thread
#define EPB (PT * EPT)  // 5120 edges per partition block
#define NBLK (N_EDGES / EPB)  // 250 partition blocks (exact)

// ---------------- workspace layout (bytes) ----------------
#define OFF_SUP   0u
#define SUP_BYTES (N_NODES * D * 2u)                 // 10,240,000 (bf16 support)
#define OFF_CNT   (OFF_SUP + SUP_BYTES)
#define OFF_OVC   (OFF_CNT + 5120u)
#define OFF_REC   (OFF_OVC + 256u)
#define REC_BYTES (NB * CAPB * 8u)                   // 15,360,000
#define OFF_OVF   (OFF_REC + REC_BYTES)
#define ZERO_INTS 1344                               // (5120+256)/4 — cnt + ovf_cnt region

// round-to-nearest-even f32 -> bf16 pair packed in one uint (a=lo, b=hi)
__device__ inline unsigned bf16pair(float a, float b) {
    unsigned ua = __float_as_uint(a);
    unsigned ub = __float_as_uint(b);
    ua = (ua + 0x7fffu + ((ua >> 16) & 1u)) >> 16;
    ub = (ub + 0x7fffu + ((ub >> 16) & 1u)) & 0xffff0000u;
    return ua | ub;
}

// ---------------------------------------------------------------------------
// Kernel 1: support = X @ W -> bf16.  512 threads: each row handled by 2
// threads (j-halves).  Block 0 also zeroes the bin/overflow counters
// (replaces the 43 us hipMemsetAsync fill kernel; stream order makes it
// visible to partition_block).
// ---------------------------------------------------------------------------
__global__ __launch_bounds__(512) void gemm_xw(const float* __restrict__ x,
                                               const float* __restrict__ w,
                                               unsigned* __restrict__ sup,
                                               int* __restrict__ zero_region) {
    __shared__ float4 Ws[D * 16];
    const int tid = threadIdx.x;
    if (blockIdx.x == 0) {
        for (int i = tid; i < ZERO_INTS; i += 512) zero_region[i] = 0;
    }
    for (int i = tid; i < D * 16; i += 512) Ws[i] = ((const float4*)w)[i];
    __syncthreads();

    const int h = tid >> 8;                 // j-half: 0 or 1
    const int row = blockIdx.x * 256 + (tid & 255);
    if (row >= N_NODES) return;

    const float4* xr = (const float4*)(x + (size_t)row * D);
    float4 acc[8];
#pragma unroll
    for (int j = 0; j < 8; ++j) acc[j] = make_float4(0.f, 0.f, 0.f, 0.f);

    for (int k4 = 0; k4 < 16; ++k4) {
        const float4 xv = xr[k4];
        const float xs[4] = {xv.x, xv.y, xv.z, xv.w};
#pragma unroll
        for (int kk = 0; kk < 4; ++kk) {
            const float xk = xs[kk];
            const int k = k4 * 4 + kk;
#pragma unroll
            for (int j = 0; j < 8; ++j) {
                const float4 wv = Ws[k * 16 + h * 8 + j];
                acc[j].x += xk * wv.x;
                acc[j].y += xk * wv.y;
                acc[j].z += xk * wv.z;
                acc[j].w += xk * wv.w;
            }
        }
    }

    // this half writes 16 uints (cols h*32 .. h*32+31) as 4 uint4 stores
    unsigned* srow = sup + (size_t)row * 32 + h * 16;
#pragma unroll
    for (int jj = 0; jj < 4; ++jj) {
        uint4 u;
        u.x = bf16pair(acc[2 * jj].x,     acc[2 * jj].y);
        u.y = bf16pair(acc[2 * jj].z,     acc[2 * jj].w);
        u.z = bf16pair(acc[2 * jj + 1].x, acc[2 * jj + 1].y);
        u.w = bf16pair(acc[2 * jj + 1].z, acc[2 * jj + 1].w);
        ((uint4*)srow)[jj] = u;
    }
}

// ---------------------------------------------------------------------------
// Kernel 2: block-batched partition.  record = (src | dst_lo<<17, weight)
// ---------------------------------------------------------------------------
__global__ __launch_bounds__(PT) void partition_block(const int* __restrict__ ei,
                                                      const float* __restrict__ ew,
                                                      int* __restrict__ cnt,
                                                      int2* __restrict__ recs,
                                                      int* __restrict__ ovf_cnt,
                                                      int* __restrict__ ovf_list) {
    __shared__ int hist[NB];   // count, then reused as global-slot cursor
    const int tid = threadIdx.x;
    const int e0 = blockIdx.x * EPB;

    for (int i = tid; i < NB; i += PT) hist[i] = 0;
    __syncthreads();

    int r_meta[EPT], r_w[EPT], r_bin[EPT];
#pragma unroll
    for (int i = 0; i < EPT; ++i) {
        const int e = e0 + i * PT + tid;
        const int dst = ei[N_EDGES + e];
        const int src = ei[e];
        r_meta[i] = src | ((dst & 63) << 17);
        r_w[i]    = __float_as_int(ew[e]);
        r_bin[i]  = dst >> 6;
        atomicAdd(&hist[r_bin[i]], 1);
    }
    __syncthreads();

    for (int b = tid; b < NB; b += PT) {
        const int c = hist[b];
        if (c > 0) hist[b] = atomicAdd(&cnt[b], c);
    }
    __syncthreads();

#pragma unroll
    for (int i = 0; i < EPT; ++i) {
        const int slot = atomicAdd(&hist[r_bin[i]], 1);
        if (slot < CAPB) {
            recs[(size_t)r_bin[i] * CAPB + slot] = make_int2(r_meta[i], r_w[i]);
        } else {
            const int q = atomicAdd(ovf_cnt, 1);
            ovf_list[q] = e0 + i * PT + tid;
        }
    }
}

// ---------------------------------------------------------------------------
// Kernel 3: per-bin gather, 1024 threads (16 waves): stage records, u16
// permutation to CSR order, then ONE 16-lane group per node with a
// software-pipelined record loop.
// ---------------------------------------------------------------------------
__global__ __launch_bounds__(1024) void gather_bins(const unsigned* __restrict__ sup,
                                                    const int* __restrict__ cnt,
                                                    const int2* __restrict__ recs,
                                                    const float* __restrict__ bias,
                                                    float* __restrict__ out) {
    __shared__ int2 lrec[CAPB];              // 12,288 B
    __shared__ unsigned short perm[CAPB];    //  3,072 B
    __shared__ int lcnt[NPB];
    __shared__ int lcur[NPB];
    __shared__ int loff[NPB + 1];
    __shared__ float4 b4[16];

    const int tid = threadIdx.x;
    const int bin = blockIdx.x;

    if (tid < 16) b4[tid] = ((const float4*)bias)[tid];
    if (tid < NPB) lcnt[tid] = 0;
    __syncthreads();

    int c = cnt[bin];
    c = c < CAPB ? c : CAPB;
    const int2* bk = recs + (size_t)bin * CAPB;

    // stage + per-node counts (1 int LDS atomic per record)
    for (int i = tid; i < c; i += 1024) {
        const int2 r = bk[i];
        lrec[i] = r;
        atomicAdd(&lcnt[(r.x >> 17) & 63], 1);
    }
    __syncthreads();

    // wave 0: exclusive scan over 64 node counts
    if (tid < 64) {
        const int my = lcnt[tid];
        int v = my;
#pragma unroll
        for (int d = 1; d < 64; d <<= 1) {
            const int o = __shfl_up(v, d);
            if (tid >= d) v += o;
        }
        loff[tid + 1] = v;
        lcur[tid] = v - my;
        if (tid == 0) loff[0] = 0;
    }
    __syncthreads();

    // permutation into CSR order (1 int LDS atomic + u16 write per record)
    for (int i = tid; i < c; i += 1024) {
        const int pos = atomicAdd(&lcur[(lrec[i].x >> 17) & 63], 1);
        perm[pos] = (unsigned short)i;
    }
    __syncthreads();

    // one 16-lane group per node; pipelined accumulate
    const int n = tid >> 4;       // node 0..63
    const int l = tid & 15;
    const int kbeg = loff[n];
    const int kend = loff[n + 1];
    float4 acc = b4[l];
    if (kbeg < kend) {
        int2 r = lrec[perm[kbeg]];
        uint2 sv = ((const uint2*)(sup + (size_t)(r.x & 0x1FFFF) * 32))[l];
        float wc = __int_as_float(r.y);
        for (int k = kbeg; k < kend; ++k) {
            const int kn = (k + 1 < kend) ? k + 1 : k;
            const int2 rn = lrec[perm[kn]];
            const uint2 svn = ((const uint2*)(sup + (size_t)(rn.x & 0x1FFFF) * 32))[l];
            acc.x += wc * __uint_as_float(sv.x << 16);
            acc.y += wc * __uint_as_float(sv.x & 0xffff0000u);
            acc.z += wc * __uint_as_float(sv.y << 16);
            acc.w += wc * __uint_as_float(sv.y & 0xffff0000u);
            sv = svn;
            wc = __int_as_float(rn.y);
        }
    }
    ((float4*)out)[(size_t)(bin * NPB + n) * 16 + l] = acc;
}

// ---------------------------------------------------------------------------
// Kernel 4: rare overflow edges -> atomic scatter (statistically zero work)
// ---------------------------------------------------------------------------
__global__ __launch_bounds__(256) void scatter_ovf(const int* __restrict__ ei,
                                                   const float* __restrict__ ew,
                                                   const unsigned* __restrict__ sup,
                                                   const int* __restrict__ ovf_cnt,
                                                   const int* __restrict__ ovf_list,
                                                   float* __restrict__ out) {
    const int n = *ovf_cnt;
    for (int i = blockIdx.x * 256 + threadIdx.x; i < n; i += gridDim.x * 256) {
        const int e = ovf_list[i];
        const int src = ei[e];
        const int dst = ei[N_EDGES + e];
        const float w = ew[e];
        const unsigned* s = sup + (size_t)src * 32;
        float* o = out + (size_t)dst * D;
        for (int j = 0; j < 32; ++j) {
            const unsigned u = s[j];
            atomicAdd(o + 2 * j,     w * __uint_as_float(u << 16));
            atomicAdd(o + 2 * j + 1, w * __uint_as_float(u & 0xffff0000u));
        }
    }
}

// ---------------------------------------------------------------------------
extern "C" void kernel_launch(void* const* d_in, const int* in_sizes, int n_in,
                              void* d_out, int out_size, void* d_ws, size_t ws_size,
                              hipStream_t stream) {
    const float* x      = (const float*)d_in[0];
    const int*   ei     = (const int*)d_in[1];
    const float* ew     = (const float*)d_in[2];
    const float* weight = (const float*)d_in[3];
    const float* bias   = (const float*)d_in[4];
    float* out = (float*)d_out;

    char* ws = (char*)d_ws;
    unsigned* sup   = (unsigned*)(ws + OFF_SUP);
    int*  cnt       = (int*)(ws + OFF_CNT);
    int*  ovf_cnt   = (int*)(ws + OFF_OVC);
    int2* recs      = (int2*)(ws + OFF_REC);
    int*  ovf_list  = (int*)(ws + OFF_OVF);

    // 1. support = X @ W (bf16) + counter zeroing (block 0)
    gemm_xw<<<(N_NODES + 255) / 256, 512, 0, stream>>>(x, weight, sup, cnt);

    // 2. block-batched partition into per-bin contiguous streams
    partition_block<<<NBLK, PT, 0, stream>>>(ei, ew, cnt, recs, ovf_cnt, ovf_list);

    // 3. per-bin gather + bias + out write (1024 threads, 1 group/node)
    gather_bins<<<NB, 1024, 0, stream>>>(sup, cnt, recs, bias, out);

    // 4. overflow cleanup (statistically empty, correctness safety net)
    scatter_ovf<<<32, 256, 0, stream>>>(ei, ew, sup, ovf_cnt, ovf_list, out);
}

// Round 8
// 82.934 us; speedup vs baseline: 5.9124x; 1.1534x over previous
//
#include <hip/hip_runtime.h>

#define N_NODES 80000
#define N_EDGES 1280000
#define D 64            // D_IN == D_OUT == 64
#define NB 1250         // bins of 64 nodes: 1250*64 = 80000
#define NPB 64          // nodes per bin
#define CAPB 1536       // per-bin record capacity (Poisson(1024) + ~16 sigma)
#define PT 1024         // partition block threads
#define EPT 5           // edges per partition thread
#define EPB (PT * EPT)  // 5120 edges per partition block
#define NBLK (N_EDGES / EPB)        // 250 partition blocks (exact)
#define GEMM_BLOCKS ((N_NODES + 511) / 512)   // 157 gemm blocks (512 rows each)

// ---------------- workspace layout (bytes) ----------------
#define OFF_SUP   0u
#define SUP_BYTES (N_NODES * D * 2u)                 // 10,240,000 (bf16 support)
#define OFF_CNT   (OFF_SUP + SUP_BYTES)
#define OFF_OVC   (OFF_CNT + 5120u)
#define OFF_REC   (OFF_OVC + 256u)
#define REC_BYTES (NB * CAPB * 8u)                   // 15,360,000
#define OFF_OVF   (OFF_REC + REC_BYTES)
#define ZERO_INTS 1344                               // cnt (1250) + pad + ovf_cnt region

// round-to-nearest-even f32 -> bf16 pair packed in one uint (a=lo, b=hi)
__device__ inline unsigned bf16pair(float a, float b) {
    unsigned ua = __float_as_uint(a);
    unsigned ub = __float_as_uint(b);
    ua = (ua + 0x7fffu + ((ua >> 16) & 1u)) >> 16;
    ub = (ub + 0x7fffu + ((ub >> 16) & 1u)) & 0xffff0000u;
    return ua | ub;
}

// ---------------------------------------------------------------------------
// Kernel 0: zero bin counters + overflow counter (tiny, 1 block)
// ---------------------------------------------------------------------------
__global__ __launch_bounds__(1024) void zero_cnt(int* __restrict__ z) {
    for (int i = threadIdx.x; i < ZERO_INTS; i += 1024) z[i] = 0;
}

// ---------------------------------------------------------------------------
// Kernel 1 (fused): blockIdx < GEMM_BLOCKS -> support = X @ W (bf16),
// else -> block-batched edge partition.  The two phases are independent
// (gemm: x,w -> sup; partition: ei,ew -> recs/cnt) and overlap on the chip.
// record = (src | dst_lo<<17, weight)
// ---------------------------------------------------------------------------
__global__ __launch_bounds__(1024) void gemm_partition(const float* __restrict__ x,
                                                       const float* __restrict__ w,
                                                       unsigned* __restrict__ sup,
                                                       const int* __restrict__ ei,
                                                       const float* __restrict__ ew,
                                                       int* __restrict__ cnt,
                                                       int2* __restrict__ recs,
                                                       int* __restrict__ ovf_cnt,
                                                       int* __restrict__ ovf_list) {
    __shared__ __align__(16) char smem[16384];   // union: Ws (16 KB) / hist (5 KB)
    const int tid = threadIdx.x;

    if (blockIdx.x < GEMM_BLOCKS) {
        // ---- GEMM branch: 512 rows/block, 2 threads per row (j-halves) ----
        float4* Ws = (float4*)smem;              // [k][j4] : 64 x 16 float4
        if (tid < 1024) Ws[tid] = ((const float4*)w)[tid];
        __syncthreads();

        const int h = tid >> 9;                  // j-half: 0 or 1
        const int row = blockIdx.x * 512 + (tid & 511);
        if (row >= N_NODES) return;

        const float4* xr = (const float4*)(x + (size_t)row * D);
        float4 acc[8];
#pragma unroll
        for (int j = 0; j < 8; ++j) acc[j] = make_float4(0.f, 0.f, 0.f, 0.f);

        for (int k4 = 0; k4 < 16; ++k4) {
            const float4 xv = xr[k4];
            const float xs[4] = {xv.x, xv.y, xv.z, xv.w};
#pragma unroll
            for (int kk = 0; kk < 4; ++kk) {
                const float xk = xs[kk];
                const int k = k4 * 4 + kk;
#pragma unroll
                for (int j = 0; j < 8; ++j) {
                    const float4 wv = Ws[k * 16 + h * 8 + j];
                    acc[j].x += xk * wv.x;
                    acc[j].y += xk * wv.y;
                    acc[j].z += xk * wv.z;
                    acc[j].w += xk * wv.w;
                }
            }
        }

        unsigned* srow = sup + (size_t)row * 32 + h * 16;
#pragma unroll
        for (int jj = 0; jj < 4; ++jj) {
            uint4 u;
            u.x = bf16pair(acc[2 * jj].x,     acc[2 * jj].y);
            u.y = bf16pair(acc[2 * jj].z,     acc[2 * jj].w);
            u.z = bf16pair(acc[2 * jj + 1].x, acc[2 * jj + 1].y);
            u.w = bf16pair(acc[2 * jj + 1].z, acc[2 * jj + 1].w);
            ((uint4*)srow)[jj] = u;
        }
    } else {
        // ---- Partition branch: LDS histogram -> 1 global atomic per
        // non-empty bin -> LDS-cursor placement into contiguous streams ----
        int* hist = (int*)smem;
        const int e0 = (blockIdx.x - GEMM_BLOCKS) * EPB;

        for (int i = tid; i < NB; i += PT) hist[i] = 0;
        __syncthreads();

        int r_meta[EPT], r_w[EPT], r_bin[EPT];
#pragma unroll
        for (int i = 0; i < EPT; ++i) {
            const int e = e0 + i * PT + tid;
            const int dst = ei[N_EDGES + e];
            const int src = ei[e];
            r_meta[i] = src | ((dst & 63) << 17);
            r_w[i]    = __float_as_int(ew[e]);
            r_bin[i]  = dst >> 6;
            atomicAdd(&hist[r_bin[i]], 1);
        }
        __syncthreads();

        for (int b = tid; b < NB; b += PT) {
            const int c = hist[b];
            if (c > 0) hist[b] = atomicAdd(&cnt[b], c);
        }
        __syncthreads();

#pragma unroll
        for (int i = 0; i < EPT; ++i) {
            const int slot = atomicAdd(&hist[r_bin[i]], 1);
            if (slot < CAPB) {
                recs[(size_t)r_bin[i] * CAPB + slot] = make_int2(r_meta[i], r_w[i]);
            } else {
                const int q = atomicAdd(ovf_cnt, 1);
                ovf_list[q] = e0 + i * PT + tid;
            }
        }
    }
}

// ---------------------------------------------------------------------------
// Kernel 2: per-bin gather, 1024 threads (16 waves): stage records, u16
// permutation to CSR order, then ONE 16-lane group per node with a
// software-pipelined record loop.
// ---------------------------------------------------------------------------
__global__ __launch_bounds__(1024) void gather_bins(const unsigned* __restrict__ sup,
                                                    const int* __restrict__ cnt,
                                                    const int2* __restrict__ recs,
                                                    const float* __restrict__ bias,
                                                    float* __restrict__ out) {
    __shared__ int2 lrec[CAPB];              // 12,288 B
    __shared__ unsigned short perm[CAPB];    //  3,072 B
    __shared__ int lcnt[NPB];
    __shared__ int lcur[NPB];
    __shared__ int loff[NPB + 1];
    __shared__ float4 b4[16];

    const int tid = threadIdx.x;
    const int bin = blockIdx.x;

    if (tid < 16) b4[tid] = ((const float4*)bias)[tid];
    if (tid < NPB) lcnt[tid] = 0;
    __syncthreads();

    int c = cnt[bin];
    c = c < CAPB ? c : CAPB;
    const int2* bk = recs + (size_t)bin * CAPB;

    // stage + per-node counts (1 int LDS atomic per record)
    for (int i = tid; i < c; i += 1024) {
        const int2 r = bk[i];
        lrec[i] = r;
        atomicAdd(&lcnt[(r.x >> 17) & 63], 1);
    }
    __syncthreads();

    // wave 0: exclusive scan over 64 node counts
    if (tid < 64) {
        const int my = lcnt[tid];
        int v = my;
#pragma unroll
        for (int d = 1; d < 64; d <<= 1) {
            const int o = __shfl_up(v, d);
            if (tid >= d) v += o;
        }
        loff[tid + 1] = v;
        lcur[tid] = v - my;
        if (tid == 0) loff[0] = 0;
    }
    __syncthreads();

    // permutation into CSR order (1 int LDS atomic + u16 write per record)
    for (int i = tid; i < c; i += 1024) {
        const int pos = atomicAdd(&lcur[(lrec[i].x >> 17) & 63], 1);
        perm[pos] = (unsigned short)i;
    }
    __syncthreads();

    // one 16-lane group per node; pipelined accumulate
    const int n = tid >> 4;       // node 0..63
    const int l = tid & 15;
    const int kbeg = loff[n];
    const int kend = loff[n + 1];
    float4 acc = b4[l];
    if (kbeg < kend) {
        int2 r = lrec[perm[kbeg]];
        uint2 sv = ((const uint2*)(sup + (size_t)(r.x & 0x1FFFF) * 32))[l];
        float wc = __int_as_float(r.y);
        for (int k = kbeg; k < kend; ++k) {
            const int kn = (k + 1 < kend) ? k + 1 : k;
            const int2 rn = lrec[perm[kn]];
            const uint2 svn = ((const uint2*)(sup + (size_t)(rn.x & 0x1FFFF) * 32))[l];
            acc.x += wc * __uint_as_float(sv.x << 16);
            acc.y += wc * __uint_as_float(sv.x & 0xffff0000u);
            acc.z += wc * __uint_as_float(sv.y << 16);
            acc.w += wc * __uint_as_float(sv.y & 0xffff0000u);
            sv = svn;
            wc = __int_as_float(rn.y);
        }
    }
    ((float4*)out)[(size_t)(bin * NPB + n) * 16 + l] = acc;
}

// ---------------------------------------------------------------------------
// Kernel 3: rare overflow edges -> atomic scatter (statistically zero work)
// ---------------------------------------------------------------------------
__global__ __launch_bounds__(256) void scatter_ovf(const int* __restrict__ ei,
                                                   const float* __restrict__ ew,
                                                   const unsigned* __restrict__ sup,
                                                   const int* __restrict__ ovf_cnt,
                                                   const int* __restrict__ ovf_list,
                                                   float* __restrict__ out) {
    const int n = *ovf_cnt;
    for (int i = blockIdx.x * 256 + threadIdx.x; i < n; i += gridDim.x * 256) {
        const int e = ovf_list[i];
        const int src = ei[e];
        const int dst = ei[N_EDGES + e];
        const float w = ew[e];
        const unsigned* s = sup + (size_t)src * 32;
        float* o = out + (size_t)dst * D;
        for (int j = 0; j < 32; ++j) {
            const unsigned u = s[j];
            atomicAdd(o + 2 * j,     w * __uint_as_float(u << 16));
            atomicAdd(o + 2 * j + 1, w * __uint_as_float(u & 0xffff0000u));
        }
    }
}

// ---------------------------------------------------------------------------
extern "C" void kernel_launch(void* const* d_in, const int* in_sizes, int n_in,
                              void* d_out, int out_size, void* d_ws, size_t ws_size,
                              hipStream_t stream) {
    const float* x      = (const float*)d_in[0];
    const int*   ei     = (const int*)d_in[1];
    const float* ew     = (const float*)d_in[2];
    const float* weight = (const float*)d_in[3];
    const float* bias   = (const float*)d_in[4];
    float* out = (float*)d_out;

    char* ws = (char*)d_ws;
    unsigned* sup   = (unsigned*)(ws + OFF_SUP);
    int*  cnt       = (int*)(ws + OFF_CNT);
    int*  ovf_cnt   = (int*)(ws + OFF_OVC);
    int2* recs      = (int2*)(ws + OFF_REC);
    int*  ovf_list  = (int*)(ws + OFF_OVF);

    // 0. zero bin/overflow counters (1 tiny block)
    zero_cnt<<<1, 1024, 0, stream>>>(cnt);

    // 1. fused: support = X @ W (bf16)  ||  edge partition into bin streams
    gemm_partition<<<GEMM_BLOCKS + NBLK, 1024, 0, stream>>>(
        x, weight, sup, ei, ew, cnt, recs, ovf_cnt, ovf_list);

    // 2. per-bin gather + bias + out write (1024 threads, 1 group/node)
    gather_bins<<<NB, 1024, 0, stream>>>(sup, cnt, recs, bias, out);

    // 3. overflow cleanup (statistically empty, correctness safety net)
    scatter_ovf<<<32, 256, 0, stream>>>(ei, ew, sup, ovf_cnt, ovf_list, out);
}

// Round 9
// 70.710 us; speedup vs baseline: 6.9344x; 1.1729x over previous
//
#include <hip/hip_runtime.h>

#define N_NODES 80000
#define N_EDGES 1280000
#define D 64            // D_IN == D_OUT == 64
#define NB 1250         // bins of 64 nodes: 1250*64 = 80000
#define NPB 64          // nodes per bin
#define CAPB 1536       // per-bin record capacity (Poisson(1024) + ~16 sigma)
#define PT 1024         // partition block threads
#define EPT 10          // edges per partition thread
#define EPB (PT * EPT)  // 10240 edges per partition block
#define NBLK (N_EDGES / EPB)            // 125 partition blocks (exact)
#define GEMM_BLOCKS ((N_NODES + 255) / 256)   // 313 gemm blocks (256 rows, 16 waves)

// ---------------- workspace layout (bytes) ----------------
#define OFF_SUP   0u
#define SUP_BYTES (N_NODES * D * 2u)                 // 10,240,000 (bf16 support)
#define OFF_CNT   (OFF_SUP + SUP_BYTES)
#define OFF_OVC   (OFF_CNT + 5120u)
#define OFF_REC   (OFF_OVC + 256u)
#define REC_BYTES (NB * CAPB * 8u)                   // 15,360,000
#define OFF_OVF   (OFF_REC + REC_BYTES)
#define ZERO_INTS 1344                               // cnt region + ovf_cnt

typedef __attribute__((ext_vector_type(8))) __bf16 bf16x8;
typedef __attribute__((ext_vector_type(4))) float  floatx4;

// scalar f32 -> bf16 RNE
__device__ inline unsigned short bf16_rne(float f) {
    unsigned u = __float_as_uint(f);
    u += 0x7fffu + ((u >> 16) & 1u);
    return (unsigned short)(u >> 16);
}

__device__ inline bf16x8 pack8(float4 a, float4 b) {
    union { unsigned short s[8]; bf16x8 v; } U;
    U.s[0] = bf16_rne(a.x); U.s[1] = bf16_rne(a.y);
    U.s[2] = bf16_rne(a.z); U.s[3] = bf16_rne(a.w);
    U.s[4] = bf16_rne(b.x); U.s[5] = bf16_rne(b.y);
    U.s[6] = bf16_rne(b.z); U.s[7] = bf16_rne(b.w);
    return U.v;
}

// ---------------------------------------------------------------------------
// Kernel 0: zero bin counters + overflow counter (tiny, 1 block)
// ---------------------------------------------------------------------------
__global__ __launch_bounds__(1024) void zero_cnt(int* __restrict__ z) {
    for (int i = threadIdx.x; i < ZERO_INTS; i += 1024) z[i] = 0;
}

// ---------------------------------------------------------------------------
// Kernel 1 (fused): blockIdx < GEMM_BLOCKS -> support = X @ W via MFMA
// (bf16 in/out, f32 accum), else -> block-batched edge partition.
// record = (src | dst_lo<<17, weight)
// ---------------------------------------------------------------------------
__global__ __launch_bounds__(1024) void gemm_partition(const float* __restrict__ x,
                                                       const float* __restrict__ w,
                                                       unsigned* __restrict__ sup,
                                                       const int* __restrict__ ei,
                                                       const float* __restrict__ ew,
                                                       int* __restrict__ cnt,
                                                       int2* __restrict__ recs,
                                                       int* __restrict__ ovf_cnt,
                                                       int* __restrict__ ovf_list) {
    // union: gemm -> wt (8 KB) + out-staging (32 KB); partition -> hist (5 KB)
    __shared__ __align__(16) char smem[40960];
    const int tid = threadIdx.x;

    if (blockIdx.x < GEMM_BLOCKS) {
        // ---- MFMA GEMM: 16 waves/block, one 16-row x 64-col tile per wave --
        const int wave = tid >> 6;
        const int lane = tid & 63;
        const int r0 = blockIdx.x * 256 + wave * 16;

        // stage W transposed -> bf16 with XOR swizzle (conflict-free B reads)
        for (int idx = tid; idx < 4096; idx += 1024) {
            const int k = idx >> 6, n = idx & 63;
            const unsigned byte = (unsigned)((n * 64 + k) * 2) ^ (unsigned)((n & 7) << 4);
            *(unsigned short*)(smem + byte) = bf16_rne(w[idx]);
        }
        __syncthreads();

        if (r0 < N_NODES) {     // 80000 % 16 == 0 -> tile fully valid
            const int mrow = lane & 15;      // A row / B col / D col lane bits
            const int q    = lane >> 4;      // k-quadrant
            const float* xr = x + (size_t)(r0 + mrow) * D;

            // A frags: k = q*8 + i (+32 for frag1)
            const bf16x8 A0 = pack8(*(const float4*)(xr + q * 8),
                                    *(const float4*)(xr + q * 8 + 4));
            const bf16x8 A1 = pack8(*(const float4*)(xr + 32 + q * 8),
                                    *(const float4*)(xr + 32 + q * 8 + 4));

            floatx4 acc[4];
#pragma unroll
            for (int t = 0; t < 4; ++t) acc[t] = (floatx4){0.f, 0.f, 0.f, 0.f};

#pragma unroll
            for (int t = 0; t < 4; ++t) {
                const int n = t * 16 + mrow;
                const unsigned b0 = (unsigned)((n * 64 + q * 8) * 2) ^ (unsigned)((n & 7) << 4);
                const unsigned b1 = (unsigned)((n * 64 + 32 + q * 8) * 2) ^ (unsigned)((n & 7) << 4);
                const bf16x8 B0 = *(const bf16x8*)(smem + b0);
                const bf16x8 B1 = *(const bf16x8*)(smem + b1);
                acc[t] = __builtin_amdgcn_mfma_f32_16x16x32_bf16(A0, B0, acc[t], 0, 0, 0);
                acc[t] = __builtin_amdgcn_mfma_f32_16x16x32_bf16(A1, B1, acc[t], 0, 0, 0);
            }

            // D: col = lane&15, row = (lane>>4)*4 + reg  (m89-verified)
            unsigned short* so = (unsigned short*)(smem + 8192) + wave * 1024;
#pragma unroll
            for (int t = 0; t < 4; ++t) {
#pragma unroll
                for (int r = 0; r < 4; ++r) {
                    so[(q * 4 + r) * 64 + t * 16 + mrow] = bf16_rne(acc[t][r]);
                }
            }
        }
        __syncthreads();
        if (r0 < N_NODES) {
            // coalesced readback: wave tile = 16 rows x 128 B, contiguous in sup
            const uint4* lo = (const uint4*)(smem + 8192 + wave * 2048);
            const uint4 v0 = lo[lane];
            const uint4 v1 = lo[64 + lane];
            char* supb = (char*)sup;
            ((uint4*)(supb + (size_t)(r0 + (lane >> 3)) * 128))[lane & 7] = v0;
            ((uint4*)(supb + (size_t)(r0 + 8 + (lane >> 3)) * 128))[lane & 7] = v1;
        }
    } else {
        // ---- Partition branch: LDS histogram -> 1 global atomic per
        // non-empty bin -> LDS-cursor placement into contiguous streams ----
        int* hist = (int*)smem;
        const int e0 = (blockIdx.x - GEMM_BLOCKS) * EPB;

        for (int i = tid; i < NB; i += PT) hist[i] = 0;
        __syncthreads();

        int r_meta[EPT], r_w[EPT], r_bin[EPT];
#pragma unroll
        for (int i = 0; i < EPT; ++i) {
            const int e = e0 + i * PT + tid;
            const int dst = ei[N_EDGES + e];
            const int src = ei[e];
            r_meta[i] = src | ((dst & 63) << 17);
            r_w[i]    = __float_as_int(ew[e]);
            r_bin[i]  = dst >> 6;
            atomicAdd(&hist[r_bin[i]], 1);
        }
        __syncthreads();

        for (int b = tid; b < NB; b += PT) {
            const int c = hist[b];
            if (c > 0) hist[b] = atomicAdd(&cnt[b], c);
        }
        __syncthreads();

#pragma unroll
        for (int i = 0; i < EPT; ++i) {
            const int slot = atomicAdd(&hist[r_bin[i]], 1);
            if (slot < CAPB) {
                recs[(size_t)r_bin[i] * CAPB + slot] = make_int2(r_meta[i], r_w[i]);
            } else {
                const int q2 = atomicAdd(ovf_cnt, 1);
                ovf_list[q2] = e0 + i * PT + tid;
            }
        }
    }
}

// ---------------------------------------------------------------------------
// Kernel 2: per-bin gather, 1024 threads (16 waves): stage records, u16
// permutation to CSR order, then ONE 16-lane group per node with a
// software-pipelined record loop.
// ---------------------------------------------------------------------------
__global__ __launch_bounds__(1024) void gather_bins(const unsigned* __restrict__ sup,
                                                    const int* __restrict__ cnt,
                                                    const int2* __restrict__ recs,
                                                    const float* __restrict__ bias,
                                                    float* __restrict__ out) {
    __shared__ int2 lrec[CAPB];              // 12,288 B
    __shared__ unsigned short perm[CAPB];    //  3,072 B
    __shared__ int lcnt[NPB];
    __shared__ int lcur[NPB];
    __shared__ int loff[NPB + 1];
    __shared__ float4 b4[16];

    const int tid = threadIdx.x;
    const int bin = blockIdx.x;

    if (tid < 16) b4[tid] = ((const float4*)bias)[tid];
    if (tid < NPB) lcnt[tid] = 0;
    __syncthreads();

    int c = cnt[bin];
    c = c < CAPB ? c : CAPB;
    const int2* bk = recs + (size_t)bin * CAPB;

    // stage + per-node counts (1 int LDS atomic per record)
    for (int i = tid; i < c; i += 1024) {
        const int2 r = bk[i];
        lrec[i] = r;
        atomicAdd(&lcnt[(r.x >> 17) & 63], 1);
    }
    __syncthreads();

    // wave 0: exclusive scan over 64 node counts
    if (tid < 64) {
        const int my = lcnt[tid];
        int v = my;
#pragma unroll
        for (int d = 1; d < 64; d <<= 1) {
            const int o = __shfl_up(v, d);
            if (tid >= d) v += o;
        }
        loff[tid + 1] = v;
        lcur[tid] = v - my;
        if (tid == 0) loff[0] = 0;
    }
    __syncthreads();

    // permutation into CSR order (1 int LDS atomic + u16 write per record)
    for (int i = tid; i < c; i += 1024) {
        const int pos = atomicAdd(&lcur[(lrec[i].x >> 17) & 63], 1);
        perm[pos] = (unsigned short)i;
    }
    __syncthreads();

    // one 16-lane group per node; pipelined accumulate
    const int n = tid >> 4;       // node 0..63
    const int l = tid & 15;
    const int kbeg = loff[n];
    const int kend = loff[n + 1];
    float4 acc = b4[l];
    if (kbeg < kend) {
        int2 r = lrec[perm[kbeg]];
        uint2 sv = ((const uint2*)(sup + (size_t)(r.x & 0x1FFFF) * 32))[l];
        float wc = __int_as_float(r.y);
        for (int k = kbeg; k < kend; ++k) {
            const int kn = (k + 1 < kend) ? k + 1 : k;
            const int2 rn = lrec[perm[kn]];
            const uint2 svn = ((const uint2*)(sup + (size_t)(rn.x & 0x1FFFF) * 32))[l];
            acc.x += wc * __uint_as_float(sv.x << 16);
            acc.y += wc * __uint_as_float(sv.x & 0xffff0000u);
            acc.z += wc * __uint_as_float(sv.y << 16);
            acc.w += wc * __uint_as_float(sv.y & 0xffff0000u);
            sv = svn;
            wc = __int_as_float(rn.y);
        }
    }
    ((float4*)out)[(size_t)(bin * NPB + n) * 16 + l] = acc;
}

// ---------------------------------------------------------------------------
// Kernel 3: rare overflow edges -> atomic scatter (statistically zero work)
// ---------------------------------------------------------------------------
__global__ __launch_bounds__(256) void scatter_ovf(const int* __restrict__ ei,
                                                   const float* __restrict__ ew,
                                                   const unsigned* __restrict__ sup,
                                                   const int* __restrict__ ovf_cnt,
                                                   const int* __restrict__ ovf_list,
                                                   float* __restrict__ out) {
    const int n = *ovf_cnt;
    for (int i = blockIdx.x * 256 + threadIdx.x; i < n; i += gridDim.x * 256) {
        const int e = ovf_list[i];
        const int src = ei[e];
        const int dst = ei[N_EDGES + e];
        const float w = ew[e];
        const unsigned* s = sup + (size_t)src * 32;
        float* o = out + (size_t)dst * D;
        for (int j = 0; j < 32; ++j) {
            const unsigned u = s[j];
            atomicAdd(o + 2 * j,     w * __uint_as_float(u << 16));
            atomicAdd(o + 2 * j + 1, w * __uint_as_float(u & 0xffff0000u));
        }
    }
}

// ---------------------------------------------------------------------------
extern "C" void kernel_launch(void* const* d_in, const int* in_sizes, int n_in,
                              void* d_out, int out_size, void* d_ws, size_t ws_size,
                              hipStream_t stream) {
    const float* x      = (const float*)d_in[0];
    const int*   ei     = (const int*)d_in[1];
    const float* ew     = (const float*)d_in[2];
    const float* weight = (const float*)d_in[3];
    const float* bias   = (const float*)d_in[4];
    float* out = (float*)d_out;

    char* ws = (char*)d_ws;
    unsigned* sup   = (unsigned*)(ws + OFF_SUP);
    int*  cnt       = (int*)(ws + OFF_CNT);
    int*  ovf_cnt   = (int*)(ws + OFF_OVC);
    int2* recs      = (int2*)(ws + OFF_REC);
    int*  ovf_list  = (int*)(ws + OFF_OVF);

    // 0. zero bin/overflow counters (1 tiny block)
    zero_cnt<<<1, 1024, 0, stream>>>(cnt);

    // 1. fused: support = X @ W (MFMA bf16)  ||  edge partition into streams
    gemm_partition<<<GEMM_BLOCKS + NBLK, 1024, 0, stream>>>(
        x, weight, sup, ei, ew, cnt, recs, ovf_cnt, ovf_list);

    // 2. per-bin gather + bias + out write (1024 threads, 1 group/node)
    gather_bins<<<NB, 1024, 0, stream>>>(sup, cnt, recs, bias, out);

    // 3. overflow cleanup (statistically empty, correctness safety net)
    scatter_ovf<<<32, 256, 0, stream>>>(ei, ew, sup, ovf_cnt, ovf_list, out);
}

// Round 10
// 70.179 us; speedup vs baseline: 6.9869x; 1.0076x over previous
//
#include <hip/hip_runtime.h>

#define N_NODES 80000
#define N_EDGES 1280000
#define D 64            // D_IN == D_OUT == 64
#define NB 1250         // bins of 64 nodes: 1250*64 = 80000
#define NPB 64          // nodes per bin
#define CAPB 1536       // per-bin record capacity (Poisson(1024) + ~16 sigma)
#define PT 1024         // partition block threads
#define EPT 10          // edges per partition thread
#define EPB (PT * EPT)  // 10240 edges per partition block
#define NBLK (N_EDGES / EPB)            // 125 partition blocks (exact)
#define GEMM_BLOCKS ((N_NODES + 255) / 256)   // 313 gemm blocks (256 rows, 16 waves)

// ---------------- workspace layout (bytes) ----------------
#define OFF_SUP   0u
#define SUP_BYTES (N_NODES * D * 2u)                 // 10,240,000 (bf16 support)
#define OFF_CNT   (OFF_SUP + SUP_BYTES)
#define OFF_OVC   (OFF_CNT + 5120u)
#define OFF_REC   (OFF_OVC + 256u)
#define REC_BYTES (NB * CAPB * 8u)                   // 15,360,000
#define OFF_OVF   (OFF_REC + REC_BYTES)
#define ZERO_INTS 1344                               // cnt region + ovf_cnt

typedef __attribute__((ext_vector_type(8))) __bf16 bf16x8;
typedef __attribute__((ext_vector_type(4))) float  floatx4;

// scalar f32 -> bf16 RNE
__device__ inline unsigned short bf16_rne(float f) {
    unsigned u = __float_as_uint(f);
    u += 0x7fffu + ((u >> 16) & 1u);
    return (unsigned short)(u >> 16);
}

__device__ inline bf16x8 pack8(float4 a, float4 b) {
    union { unsigned short s[8]; bf16x8 v; } U;
    U.s[0] = bf16_rne(a.x); U.s[1] = bf16_rne(a.y);
    U.s[2] = bf16_rne(a.z); U.s[3] = bf16_rne(a.w);
    U.s[4] = bf16_rne(b.x); U.s[5] = bf16_rne(b.y);
    U.s[6] = bf16_rne(b.z); U.s[7] = bf16_rne(b.w);
    return U.v;
}

// ---------------------------------------------------------------------------
// Kernel 0: zero bin counters + overflow counter (tiny, 1 block)
// ---------------------------------------------------------------------------
__global__ __launch_bounds__(1024) void zero_cnt(int* __restrict__ z) {
    for (int i = threadIdx.x; i < ZERO_INTS; i += 1024) z[i] = 0;
}

// ---------------------------------------------------------------------------
// Kernel 1 (fused): blockIdx < GEMM_BLOCKS -> support = X @ W via MFMA
// (bf16 in/out, f32 accum), else -> block-batched edge partition.
// record = (src | dst_lo<<17, weight)
// ---------------------------------------------------------------------------
__global__ __launch_bounds__(1024) void gemm_partition(const float* __restrict__ x,
                                                       const float* __restrict__ w,
                                                       unsigned* __restrict__ sup,
                                                       const int* __restrict__ ei,
                                                       const float* __restrict__ ew,
                                                       int* __restrict__ cnt,
                                                       int2* __restrict__ recs,
                                                       int* __restrict__ ovf_cnt,
                                                       int* __restrict__ ovf_list) {
    // union: gemm -> wt (8 KB) + out-staging (32 KB); partition -> hist (5 KB)
    __shared__ __align__(16) char smem[40960];
    const int tid = threadIdx.x;

    if (blockIdx.x < GEMM_BLOCKS) {
        // ---- MFMA GEMM: 16 waves/block, one 16-row x 64-col tile per wave --
        const int wave = tid >> 6;
        const int lane = tid & 63;
        const int r0 = blockIdx.x * 256 + wave * 16;

        // stage W transposed -> bf16 with XOR swizzle (conflict-free B reads)
        for (int idx = tid; idx < 4096; idx += 1024) {
            const int k = idx >> 6, n = idx & 63;
            const unsigned byte = (unsigned)((n * 64 + k) * 2) ^ (unsigned)((n & 7) << 4);
            *(unsigned short*)(smem + byte) = bf16_rne(w[idx]);
        }
        __syncthreads();

        if (r0 < N_NODES) {     // 80000 % 16 == 0 -> tile fully valid
            const int mrow = lane & 15;      // A row / B col / D col lane bits
            const int q    = lane >> 4;      // k-quadrant
            const float* xr = x + (size_t)(r0 + mrow) * D;

            // A frags: k = q*8 + i (+32 for frag1)
            const bf16x8 A0 = pack8(*(const float4*)(xr + q * 8),
                                    *(const float4*)(xr + q * 8 + 4));
            const bf16x8 A1 = pack8(*(const float4*)(xr + 32 + q * 8),
                                    *(const float4*)(xr + 32 + q * 8 + 4));

            floatx4 acc[4];
#pragma unroll
            for (int t = 0; t < 4; ++t) acc[t] = (floatx4){0.f, 0.f, 0.f, 0.f};

#pragma unroll
            for (int t = 0; t < 4; ++t) {
                const int n = t * 16 + mrow;
                const unsigned b0 = (unsigned)((n * 64 + q * 8) * 2) ^ (unsigned)((n & 7) << 4);
                const unsigned b1 = (unsigned)((n * 64 + 32 + q * 8) * 2) ^ (unsigned)((n & 7) << 4);
                const bf16x8 B0 = *(const bf16x8*)(smem + b0);
                const bf16x8 B1 = *(const bf16x8*)(smem + b1);
                acc[t] = __builtin_amdgcn_mfma_f32_16x16x32_bf16(A0, B0, acc[t], 0, 0, 0);
                acc[t] = __builtin_amdgcn_mfma_f32_16x16x32_bf16(A1, B1, acc[t], 0, 0, 0);
            }

            // D: col = lane&15, row = (lane>>4)*4 + reg  (m89-verified)
            unsigned short* so = (unsigned short*)(smem + 8192) + wave * 1024;
#pragma unroll
            for (int t = 0; t < 4; ++t) {
#pragma unroll
                for (int r = 0; r < 4; ++r) {
                    so[(q * 4 + r) * 64 + t * 16 + mrow] = bf16_rne(acc[t][r]);
                }
            }
        }
        __syncthreads();
        if (r0 < N_NODES) {
            // coalesced readback: wave tile = 16 rows x 128 B, contiguous in sup
            const uint4* lo = (const uint4*)(smem + 8192 + wave * 2048);
            const uint4 v0 = lo[lane];
            const uint4 v1 = lo[64 + lane];
            char* supb = (char*)sup;
            ((uint4*)(supb + (size_t)(r0 + (lane >> 3)) * 128))[lane & 7] = v0;
            ((uint4*)(supb + (size_t)(r0 + 8 + (lane >> 3)) * 128))[lane & 7] = v1;
        }
    } else {
        // ---- Partition branch: LDS histogram -> 1 global atomic per
        // non-empty bin -> LDS-cursor placement into contiguous streams ----
        int* hist = (int*)smem;
        const int e0 = (blockIdx.x - GEMM_BLOCKS) * EPB;

        for (int i = tid; i < NB; i += PT) hist[i] = 0;
        __syncthreads();

        int r_meta[EPT], r_w[EPT], r_bin[EPT];
#pragma unroll
        for (int i = 0; i < EPT; ++i) {
            const int e = e0 + i * PT + tid;
            const int dst = ei[N_EDGES + e];
            const int src = ei[e];
            r_meta[i] = src | ((dst & 63) << 17);
            r_w[i]    = __float_as_int(ew[e]);
            r_bin[i]  = dst >> 6;
            atomicAdd(&hist[r_bin[i]], 1);
        }
        __syncthreads();

        for (int b = tid; b < NB; b += PT) {
            const int c = hist[b];
            if (c > 0) hist[b] = atomicAdd(&cnt[b], c);
        }
        __syncthreads();

#pragma unroll
        for (int i = 0; i < EPT; ++i) {
            const int slot = atomicAdd(&hist[r_bin[i]], 1);
            if (slot < CAPB) {
                recs[(size_t)r_bin[i] * CAPB + slot] = make_int2(r_meta[i], r_w[i]);
            } else {
                const int q2 = atomicAdd(ovf_cnt, 1);
                ovf_list[q2] = e0 + i * PT + tid;
            }
        }
    }
}

// ---------------------------------------------------------------------------
// Kernel 2: per-bin gather, 1024 threads (16 waves): stage records, place
// directly into node-sorted lcsr (no perm indirection), then ONE 16-lane
// group per node with a 2-deep software-pipelined record loop.
// ---------------------------------------------------------------------------
__global__ __launch_bounds__(1024) void gather_bins(const unsigned* __restrict__ sup,
                                                    const int* __restrict__ cnt,
                                                    const int2* __restrict__ recs,
                                                    const float* __restrict__ bias,
                                                    float* __restrict__ out) {
    __shared__ int2 lrec[CAPB];              // 12,288 B (staged, arrival order)
    __shared__ int2 lcsr[CAPB];              // 12,288 B (node-sorted)
    __shared__ int lcnt[NPB];
    __shared__ int lcur[NPB];
    __shared__ int loff[NPB + 1];
    __shared__ float4 b4[16];

    const int tid = threadIdx.x;
    const int bin = blockIdx.x;

    if (tid < 16) b4[tid] = ((const float4*)bias)[tid];
    if (tid < NPB) lcnt[tid] = 0;
    __syncthreads();

    int c = cnt[bin];
    c = c < CAPB ? c : CAPB;
    const int2* bk = recs + (size_t)bin * CAPB;

    // stage + per-node counts (1 int LDS atomic per record)
    for (int i = tid; i < c; i += 1024) {
        const int2 r = bk[i];
        lrec[i] = r;
        atomicAdd(&lcnt[(r.x >> 17) & 63], 1);
    }
    __syncthreads();

    // wave 0: exclusive scan over 64 node counts
    if (tid < 64) {
        const int my = lcnt[tid];
        int v = my;
#pragma unroll
        for (int d = 1; d < 64; d <<= 1) {
            const int o = __shfl_up(v, d);
            if (tid >= d) v += o;
        }
        loff[tid + 1] = v;
        lcur[tid] = v - my;
        if (tid == 0) loff[0] = 0;
    }
    __syncthreads();

    // place records directly into node-sorted order
    for (int i = tid; i < c; i += 1024) {
        const int2 r = lrec[i];
        const int pos = atomicAdd(&lcur[(r.x >> 17) & 63], 1);
        lcsr[pos] = r;
    }
    __syncthreads();

    // one 16-lane group per node; 2-deep pipelined accumulate
    const int n = tid >> 4;       // node 0..63
    const int l = tid & 15;
    int k = loff[n];
    const int kend = loff[n + 1];
    float4 acc = b4[l];
    if (k < kend) {
        const int klast = kend - 1;
        int2 r0 = lcsr[k];
        uint2 sv0 = ((const uint2*)(sup + (size_t)(r0.x & 0x1FFFF) * 32))[l];
        const int kp1 = (k + 1 < klast) ? k + 1 : klast;
        int2 r1 = lcsr[kp1];
        uint2 sv1 = ((const uint2*)(sup + (size_t)(r1.x & 0x1FFFF) * 32))[l];
        for (; k < kend; ++k) {
            const int kp2 = (k + 2 < klast) ? k + 2 : klast;
            const int2 rn = lcsr[kp2];
            const uint2 svn = ((const uint2*)(sup + (size_t)(rn.x & 0x1FFFF) * 32))[l];
            const float wc = __int_as_float(r0.y);
            acc.x += wc * __uint_as_float(sv0.x << 16);
            acc.y += wc * __uint_as_float(sv0.x & 0xffff0000u);
            acc.z += wc * __uint_as_float(sv0.y << 16);
            acc.w += wc * __uint_as_float(sv0.y & 0xffff0000u);
            r0 = r1; sv0 = sv1;
            r1 = rn; sv1 = svn;
        }
    }
    ((float4*)out)[(size_t)(bin * NPB + n) * 16 + l] = acc;
}

// ---------------------------------------------------------------------------
// Kernel 3: rare overflow edges -> atomic scatter (statistically zero work)
// ---------------------------------------------------------------------------
__global__ __launch_bounds__(256) void scatter_ovf(const int* __restrict__ ei,
                                                   const float* __restrict__ ew,
                                                   const unsigned* __restrict__ sup,
                                                   const int* __restrict__ ovf_cnt,
                                                   const int* __restrict__ ovf_list,
                                                   float* __restrict__ out) {
    const int n = *ovf_cnt;
    for (int i = blockIdx.x * 256 + threadIdx.x; i < n; i += gridDim.x * 256) {
        const int e = ovf_list[i];
        const int src = ei[e];
        const int dst = ei[N_EDGES + e];
        const float w = ew[e];
        const unsigned* s = sup + (size_t)src * 32;
        float* o = out + (size_t)dst * D;
        for (int j = 0; j < 32; ++j) {
            const unsigned u = s[j];
            atomicAdd(o + 2 * j,     w * __uint_as_float(u << 16));
            atomicAdd(o + 2 * j + 1, w * __uint_as_float(u & 0xffff0000u));
        }
    }
}

// ---------------------------------------------------------------------------
extern "C" void kernel_launch(void* const* d_in, const int* in_sizes, int n_in,
                              void* d_out, int out_size, void* d_ws, size_t ws_size,
                              hipStream_t stream) {
    const float* x      = (const float*)d_in[0];
    const int*   ei     = (const int*)d_in[1];
    const float* ew     = (const float*)d_in[2];
    const float* weight = (const float*)d_in[3];
    const float* bias   = (const float*)d_in[4];
    float* out = (float*)d_out;

    char* ws = (char*)d_ws;
    unsigned* sup   = (unsigned*)(ws + OFF_SUP);
    int*  cnt       = (int*)(ws + OFF_CNT);
    int*  ovf_cnt   = (int*)(ws + OFF_OVC);
    int2* recs      = (int2*)(ws + OFF_REC);
    int*  ovf_list  = (int*)(ws + OFF_OVF);

    // 0. zero bin/overflow counters (1 tiny block)
    zero_cnt<<<1, 1024, 0, stream>>>(cnt);

    // 1. fused: support = X @ W (MFMA bf16)  ||  edge partition into streams
    gemm_partition<<<GEMM_BLOCKS + NBLK, 1024, 0, stream>>>(
        x, weight, sup, ei, ew, cnt, recs, ovf_cnt, ovf_list);

    // 2. per-bin gather + bias + out write (1024 threads, 1 group/node)
    gather_bins<<<NB, 1024, 0, stream>>>(sup, cnt, recs, bias, out);

    // 3. overflow cleanup (statistically empty, correctness safety net)
    scatter_ovf<<<32, 256, 0, stream>>>(ei, ew, sup, ovf_cnt, ovf_list, out);
}

// Round 11
// 61.742 us; speedup vs baseline: 7.9417x; 1.1367x over previous
//
#include <hip/hip_runtime.h>

#define N_NODES 80000
#define N_EDGES 1280000
#define D 64            // D_IN == D_OUT == 64
#define NB 1250         // bins of 64 nodes: 1250*64 = 80000
#define NPB 64          // nodes per bin
#define CAPB 1536       // per-bin record capacity (Poisson(1024) + ~16 sigma)
#define PT 1024         // partition block threads
#define EPT 10          // edges per partition thread
#define EPB (PT * EPT)  // 10240 edges per partition block
#define NBLK (N_EDGES / EPB)            // 125 partition blocks (exact)
#define GEMM_BLOCKS ((N_NODES + 255) / 256)   // 313 gemm blocks (256 rows, 16 waves)

// ---------------- workspace layout (bytes) ----------------
#define OFF_SUP   0u
#define SUP_BYTES (N_NODES * D * 2u)                 // 10,240,000 (bf16 support)
#define OFF_CNT   (OFF_SUP + SUP_BYTES)
#define OFF_OVC   (OFF_CNT + 5120u)
#define OFF_REC   (OFF_OVC + 256u)
#define REC_BYTES (NB * CAPB * 8u)                   // 15,360,000
#define OFF_OVF   (OFF_REC + REC_BYTES)
#define ZERO_INTS 1344                               // cnt region + ovf_cnt

typedef __attribute__((ext_vector_type(8))) __bf16 bf16x8;
typedef __attribute__((ext_vector_type(4))) float  floatx4;

// scalar f32 -> bf16 RNE
__device__ inline unsigned short bf16_rne(float f) {
    unsigned u = __float_as_uint(f);
    u += 0x7fffu + ((u >> 16) & 1u);
    return (unsigned short)(u >> 16);
}

__device__ inline bf16x8 pack8(float4 a, float4 b) {
    union { unsigned short s[8]; bf16x8 v; } U;
    U.s[0] = bf16_rne(a.x); U.s[1] = bf16_rne(a.y);
    U.s[2] = bf16_rne(a.z); U.s[3] = bf16_rne(a.w);
    U.s[4] = bf16_rne(b.x); U.s[5] = bf16_rne(b.y);
    U.s[6] = bf16_rne(b.z); U.s[7] = bf16_rne(b.w);
    return U.v;
}

// ---------------------------------------------------------------------------
// Kernel 0: zero bin counters + overflow counter (tiny, 1 block)
// ---------------------------------------------------------------------------
__global__ __launch_bounds__(1024) void zero_cnt(int* __restrict__ z) {
    for (int i = threadIdx.x; i < ZERO_INTS; i += 1024) z[i] = 0;
}

// ---------------------------------------------------------------------------
// Kernel 1 (fused): blockIdx < GEMM_BLOCKS -> support = X @ W via MFMA
// (bf16 in/out, f32 accum), else -> block-batched edge partition.
// record = (src | dst_lo<<17, weight)
// ---------------------------------------------------------------------------
__global__ __launch_bounds__(1024) void gemm_partition(const float* __restrict__ x,
                                                       const float* __restrict__ w,
                                                       unsigned* __restrict__ sup,
                                                       const int* __restrict__ ei,
                                                       const float* __restrict__ ew,
                                                       int* __restrict__ cnt,
                                                       int2* __restrict__ recs,
                                                       int* __restrict__ ovf_cnt,
                                                       int* __restrict__ ovf_list) {
    // union: gemm -> wt (8 KB) + out-staging (32 KB); partition -> hist (5 KB)
    __shared__ __align__(16) char smem[40960];
    const int tid = threadIdx.x;

    if (blockIdx.x < GEMM_BLOCKS) {
        // ---- MFMA GEMM: 16 waves/block, one 16-row x 64-col tile per wave --
        const int wave = tid >> 6;
        const int lane = tid & 63;
        const int r0 = blockIdx.x * 256 + wave * 16;

        // stage W transposed -> bf16 with XOR swizzle (conflict-free B reads)
        for (int idx = tid; idx < 4096; idx += 1024) {
            const int k = idx >> 6, n = idx & 63;
            const unsigned byte = (unsigned)((n * 64 + k) * 2) ^ (unsigned)((n & 7) << 4);
            *(unsigned short*)(smem + byte) = bf16_rne(w[idx]);
        }
        __syncthreads();

        if (r0 < N_NODES) {     // 80000 % 16 == 0 -> tile fully valid
            const int mrow = lane & 15;      // A row / B col / D col lane bits
            const int q    = lane >> 4;      // k-quadrant
            const float* xr = x + (size_t)(r0 + mrow) * D;

            // A frags: k = q*8 + i (+32 for frag1)
            const bf16x8 A0 = pack8(*(const float4*)(xr + q * 8),
                                    *(const float4*)(xr + q * 8 + 4));
            const bf16x8 A1 = pack8(*(const float4*)(xr + 32 + q * 8),
                                    *(const float4*)(xr + 32 + q * 8 + 4));

            floatx4 acc[4];
#pragma unroll
            for (int t = 0; t < 4; ++t) acc[t] = (floatx4){0.f, 0.f, 0.f, 0.f};

#pragma unroll
            for (int t = 0; t < 4; ++t) {
                const int n = t * 16 + mrow;
                const unsigned b0 = (unsigned)((n * 64 + q * 8) * 2) ^ (unsigned)((n & 7) << 4);
                const unsigned b1 = (unsigned)((n * 64 + 32 + q * 8) * 2) ^ (unsigned)((n & 7) << 4);
                const bf16x8 B0 = *(const bf16x8*)(smem + b0);
                const bf16x8 B1 = *(const bf16x8*)(smem + b1);
                acc[t] = __builtin_amdgcn_mfma_f32_16x16x32_bf16(A0, B0, acc[t], 0, 0, 0);
                acc[t] = __builtin_amdgcn_mfma_f32_16x16x32_bf16(A1, B1, acc[t], 0, 0, 0);
            }

            // D: col = lane&15, row = (lane>>4)*4 + reg  (m89-verified)
            unsigned short* so = (unsigned short*)(smem + 8192) + wave * 1024;
#pragma unroll
            for (int t = 0; t < 4; ++t) {
#pragma unroll
                for (int r = 0; r < 4; ++r) {
                    so[(q * 4 + r) * 64 + t * 16 + mrow] = bf16_rne(acc[t][r]);
                }
            }
        }
        __syncthreads();
        if (r0 < N_NODES) {
            // coalesced readback: wave tile = 16 rows x 128 B, contiguous in sup
            const uint4* lo = (const uint4*)(smem + 8192 + wave * 2048);
            const uint4 v0 = lo[lane];
            const uint4 v1 = lo[64 + lane];
            char* supb = (char*)sup;
            ((uint4*)(supb + (size_t)(r0 + (lane >> 3)) * 128))[lane & 7] = v0;
            ((uint4*)(supb + (size_t)(r0 + 8 + (lane >> 3)) * 128))[lane & 7] = v1;
        }
    } else {
        // ---- Partition branch: LDS histogram -> 1 global atomic per
        // non-empty bin -> LDS-cursor placement into contiguous streams ----
        int* hist = (int*)smem;
        const int e0 = (blockIdx.x - GEMM_BLOCKS) * EPB;

        for (int i = tid; i < NB; i += PT) hist[i] = 0;
        __syncthreads();

        int r_meta[EPT], r_w[EPT], r_bin[EPT];
#pragma unroll
        for (int i = 0; i < EPT; ++i) {
            const int e = e0 + i * PT + tid;
            const int dst = ei[N_EDGES + e];
            const int src = ei[e];
            r_meta[i] = src | ((dst & 63) << 17);
            r_w[i]    = __float_as_int(ew[e]);
            r_bin[i]  = dst >> 6;
            atomicAdd(&hist[r_bin[i]], 1);
        }
        __syncthreads();

        for (int b = tid; b < NB; b += PT) {
            const int c = hist[b];
            if (c > 0) hist[b] = atomicAdd(&cnt[b], c);
        }
        __syncthreads();

#pragma unroll
        for (int i = 0; i < EPT; ++i) {
            const int slot = atomicAdd(&hist[r_bin[i]], 1);
            if (slot < CAPB) {
                recs[(size_t)r_bin[i] * CAPB + slot] = make_int2(r_meta[i], r_w[i]);
            } else {
                const int q2 = atomicAdd(ovf_cnt, 1);
                ovf_list[q2] = e0 + i * PT + tid;
            }
        }
    }
}

// ---------------------------------------------------------------------------
// Kernel 2: per-bin gather, 512 threads (8 waves, 4 blocks/CU): stage
// records, node-sort into lcsr, then ONE 8-lane group per node with 16 B
// (uint4) sup loads — 8 FMA-pairs per record per lane.  Overflow edges for
// this bin are merged into the register accumulators (no separate kernel).
// ---------------------------------------------------------------------------
__global__ __launch_bounds__(512) void gather_bins(const unsigned* __restrict__ sup,
                                                   const int* __restrict__ cnt,
                                                   const int2* __restrict__ recs,
                                                   const float* __restrict__ bias,
                                                   const int* __restrict__ ei,
                                                   const float* __restrict__ ew,
                                                   const int* __restrict__ ovf_cnt,
                                                   const int* __restrict__ ovf_list,
                                                   float* __restrict__ out) {
    __shared__ int2 lrec[CAPB];              // 12,288 B (staged, arrival order)
    __shared__ int2 lcsr[CAPB];              // 12,288 B (node-sorted)
    __shared__ int lcnt[NPB];
    __shared__ int lcur[NPB];
    __shared__ int loff[NPB + 1];

    const int tid = threadIdx.x;
    const int bin = blockIdx.x;

    if (tid < NPB) lcnt[tid] = 0;
    __syncthreads();

    int c = cnt[bin];
    c = c < CAPB ? c : CAPB;
    const int2* bk = recs + (size_t)bin * CAPB;

    // stage + per-node counts (1 int LDS atomic per record)
    for (int i = tid; i < c; i += 512) {
        const int2 r = bk[i];
        lrec[i] = r;
        atomicAdd(&lcnt[(r.x >> 17) & 63], 1);
    }
    __syncthreads();

    // wave 0: exclusive scan over 64 node counts
    if (tid < 64) {
        const int my = lcnt[tid];
        int v = my;
#pragma unroll
        for (int d = 1; d < 64; d <<= 1) {
            const int o = __shfl_up(v, d);
            if (tid >= d) v += o;
        }
        loff[tid + 1] = v;
        lcur[tid] = v - my;
        if (tid == 0) loff[0] = 0;
    }
    __syncthreads();

    // place records directly into node-sorted order
    for (int i = tid; i < c; i += 512) {
        const int2 r = lrec[i];
        const int pos = atomicAdd(&lcur[(r.x >> 17) & 63], 1);
        lcsr[pos] = r;
    }
    __syncthreads();

    // one 8-lane group per node; lane l owns channels [l*8, l*8+8)
    const int n = tid >> 3;       // node 0..63
    const int l = tid & 7;
    float4 accA = ((const float4*)bias)[l * 2];
    float4 accB = ((const float4*)bias)[l * 2 + 1];

    const int kend = loff[n + 1];
    for (int k = loff[n]; k < kend; ++k) {
        const int2 r = lcsr[k];                       // broadcast in group
        const float wc = __int_as_float(r.y);
        const uint4 sv = ((const uint4*)(sup + (size_t)(r.x & 0x1FFFF) * 32))[l];
        accA.x += wc * __uint_as_float(sv.x << 16);
        accA.y += wc * __uint_as_float(sv.x & 0xffff0000u);
        accA.z += wc * __uint_as_float(sv.y << 16);
        accA.w += wc * __uint_as_float(sv.y & 0xffff0000u);
        accB.x += wc * __uint_as_float(sv.z << 16);
        accB.y += wc * __uint_as_float(sv.z & 0xffff0000u);
        accB.z += wc * __uint_as_float(sv.w << 16);
        accB.w += wc * __uint_as_float(sv.w & 0xffff0000u);
    }

    // overflow merge (statistically zero entries; correctness safety net)
    const int novf = *ovf_cnt;
    for (int i = 0; i < novf; ++i) {
        const int e = ovf_list[i];
        const int dst = ei[N_EDGES + e];
        if ((dst >> 6) == bin && (dst & 63) == n) {
            const float wv = ew[e];
            const uint4 sv = ((const uint4*)(sup + (size_t)ei[e] * 32))[l];
            accA.x += wv * __uint_as_float(sv.x << 16);
            accA.y += wv * __uint_as_float(sv.x & 0xffff0000u);
            accA.z += wv * __uint_as_float(sv.y << 16);
            accA.w += wv * __uint_as_float(sv.y & 0xffff0000u);
            accB.x += wv * __uint_as_float(sv.z << 16);
            accB.y += wv * __uint_as_float(sv.z & 0xffff0000u);
            accB.z += wv * __uint_as_float(sv.w << 16);
            accB.w += wv * __uint_as_float(sv.w & 0xffff0000u);
        }
    }

    float4* orow = (float4*)(out + (size_t)(bin * NPB + n) * D);
    orow[l * 2]     = accA;
    orow[l * 2 + 1] = accB;
}

// ---------------------------------------------------------------------------
extern "C" void kernel_launch(void* const* d_in, const int* in_sizes, int n_in,
                              void* d_out, int out_size, void* d_ws, size_t ws_size,
                              hipStream_t stream) {
    const float* x      = (const float*)d_in[0];
    const int*   ei     = (const int*)d_in[1];
    const float* ew     = (const float*)d_in[2];
    const float* weight = (const float*)d_in[3];
    const float* bias   = (const float*)d_in[4];
    float* out = (float*)d_out;

    char* ws = (char*)d_ws;
    unsigned* sup   = (unsigned*)(ws + OFF_SUP);
    int*  cnt       = (int*)(ws + OFF_CNT);
    int*  ovf_cnt   = (int*)(ws + OFF_OVC);
    int2* recs      = (int2*)(ws + OFF_REC);
    int*  ovf_list  = (int*)(ws + OFF_OVF);

    // 0. zero bin/overflow counters (1 tiny block)
    zero_cnt<<<1, 1024, 0, stream>>>(cnt);

    // 1. fused: support = X @ W (MFMA bf16)  ||  edge partition into streams
    gemm_partition<<<GEMM_BLOCKS + NBLK, 1024, 0, stream>>>(
        x, weight, sup, ei, ew, cnt, recs, ovf_cnt, ovf_list);

    // 2. per-bin gather + bias + overflow merge + out write
    gather_bins<<<NB, 512, 0, stream>>>(sup, cnt, recs, bias,
                                        ei, ew, ovf_cnt, ovf_list, out);
}